// Round 1
// baseline (408.277 us; speedup 1.0000x reference)
//
#include <hip/hip_runtime.h>
#include <math.h>

#define B_ 4
#define C_ 128
#define H_ 256
#define W_ 256
#define NK 2048
#define NP 8
#define HW_ (H_*W_)
#define MAXOFF 64.0f

// ---------------- K0: transpose x (B,C,H,W) -> xt (B,H,W,C) ----------------
__global__ __launch_bounds__(256) void k_transpose(const float* __restrict__ x,
                                                   float* __restrict__ xt) {
    __shared__ float tile[32][33];
    int bid = blockIdx.x;
    int xb = bid & 7;  bid >>= 3;   // W/32 = 8
    int cb = bid & 3;  bid >>= 2;   // C/32 = 4
    int y  = bid & 255; bid >>= 8;  // H
    int i  = bid;                   // B
    int tx  = threadIdx.x & 31;
    int ty0 = threadIdx.x >> 5;     // 0..7
    const float* src = x + ((size_t)(i*C_ + cb*32)*H_ + y)*W_ + xb*32;
    #pragma unroll
    for (int k = 0; k < 4; ++k) {
        int c = ty0 + k*8;
        tile[c][tx] = src[(size_t)c*HW_ + tx];
    }
    __syncthreads();
    float* dst = xt + ((size_t)(i*H_ + y)*W_ + xb*32)*C_ + cb*32;
    #pragma unroll
    for (int k = 0; k < 4; ++k) {
        int xo = ty0 + k*8;
        dst[(size_t)xo*C_ + tx] = tile[tx][xo];
    }
}

// ---------------- K1: per-keypoint patch conv + MLP -> offsets & positions --
template<bool XT>
__global__ __launch_bounds__(64) void k_offsets(const float* __restrict__ xin,
        const float* __restrict__ kpts, const float* __restrict__ W1,
        const float* __restrict__ b1, const float* __restrict__ W2,
        const float* __restrict__ b2, float* __restrict__ out_off,
        float* __restrict__ pos) {
    __shared__ float pL[1152];   // [a][b][c]
    __shared__ float hL[16];
    __shared__ float oL[16];
    int bid = blockIdx.x;            // = i*NK + n
    int i = bid >> 11;
    int t = threadIdx.x;

    float kx = kpts[(size_t)bid*2 + 0];
    float ky = kpts[(size_t)bid*2 + 1];
    float kwhx = (kx*0.5f + 0.5f) * (float)(W_-1);
    float kwhy = (ky*0.5f + 0.5f) * (float)(H_-1);
    int cx = (int)kwhx - 1; cx = cx < 0 ? 0 : (cx > 252 ? 252 : cx);
    int cy = (int)kwhy - 1; cy = cy < 0 ? 0 : (cy > 252 ? 252 : cy);

    if (XT) {
        #pragma unroll
        for (int a = 0; a < 3; ++a) {
            const float* src = xin + ((size_t)(i*H_ + cy + a)*W_ + cx)*C_;
            for (int j = t; j < 384; j += 64) pL[a*384 + j] = src[j];
        }
    } else {
        for (int e = t; e < 1152; e += 64) {
            int a = e/384; int r = e - a*384; int b = r >> 7; int c = r & 127;
            pL[e] = xin[(((size_t)(i*C_ + c))*H_ + cy + a)*W_ + cx + b];
        }
    }
    __syncthreads();

    int o = t & 15;
    int chunk = t >> 4;              // 0..3
    float partial = 0.f;
    const float* w1r = W1 + o*1152;  // layout [o][c][a][b]
    for (int c = chunk*32; c < chunk*32 + 32; ++c) {
        #pragma unroll
        for (int ab = 0; ab < 9; ++ab) {
            const int a = ab/3, b = ab - (ab/3)*3;
            partial += w1r[c*9 + ab] * pL[a*384 + b*128 + c];
        }
    }
    partial += __shfl_xor(partial, 16);
    partial += __shfl_xor(partial, 32);
    float h1 = fmaxf(partial + b1[o], 0.f);
    if (t < 16) hL[t] = h1;
    __syncthreads();
    if (t < 16) {
        float acc = b2[t];
        const float* w2r = W2 + t*16;
        #pragma unroll
        for (int oo = 0; oo < 16; ++oo) acc += w2r[oo]*hL[oo];
        acc = fminf(fmaxf(acc, -MAXOFF), MAXOFF);
        oL[t] = acc;
    }
    __syncthreads();
    if (t < 8) {
        float ox = oL[t], oy = oL[8 + t];
        size_t base = ((size_t)bid*NP + t)*2;
        out_off[base]   = ox;
        out_off[base+1] = oy;
        pos[base]   = kwhx + ox;
        pos[base+1] = kwhy + oy;
    }
}

// ------------- K2: bilinear gather + sf_w matmul + SELU (+opt fused agg) ----
template<bool XT, bool FUSED>
__global__ __launch_bounds__(128) void k_sample(const float* __restrict__ xin,
        const float* __restrict__ pos, const float* __restrict__ sf_w,
        const float* __restrict__ agg_w, float* __restrict__ dst) {
    __shared__ __align__(16) float featL[NP*C_];
    __shared__ __align__(16) float gL[NP*C_];
    __shared__ float pp[16];
    int bid = blockIdx.x;           // keypoint global index
    int i = bid >> 11;
    int c = threadIdx.x;            // 0..127
    if (c < 16) pp[c] = pos[(size_t)bid*16 + c];
    __syncthreads();

    #pragma unroll
    for (int p = 0; p < NP; ++p) {
        float px = pp[p*2], py = pp[p*2+1];
        float x0f = floorf(px), y0f = floorf(py);
        int x0 = (int)x0f, y0 = (int)y0f;
        float wx1 = px - x0f, wy1 = py - y0f;
        float wx0 = 1.f - wx1, wy0 = 1.f - wy1;
        float acc = 0.f;
        #pragma unroll
        for (int tap = 0; tap < 4; ++tap) {
            int xi = x0 + (tap & 1);
            int yi = y0 + (tap >> 1);
            float w = ((tap & 1) ? wx1 : wx0) * ((tap >> 1) ? wy1 : wy0);
            bool valid = (xi >= 0) & (xi < W_) & (yi >= 0) & (yi < H_);
            int xc = min(max(xi, 0), W_-1);
            int yc = min(max(yi, 0), H_-1);
            float v;
            if (XT) v = xin[((size_t)(i*H_ + yc)*W_ + xc)*C_ + c];
            else    v = xin[(((size_t)(i*C_ + c))*H_ + yc)*W_ + xc];
            acc += (valid ? w : 0.f) * v;
        }
        featL[p*C_ + c] = acc;
    }
    __syncthreads();

    // sf transform: thread c plays role of output channel o
    float acc[NP];
    #pragma unroll
    for (int p = 0; p < NP; ++p) acc[p] = 0.f;
    const float4* sfr = (const float4*)(sf_w + (size_t)c*C_);
    const float4* fL4 = (const float4*)featL;
    for (int c4 = 0; c4 < C_/4; ++c4) {
        float4 wv = sfr[c4];
        #pragma unroll
        for (int p = 0; p < NP; ++p) {
            float4 f = fL4[p*(C_/4) + c4];
            acc[p] += wv.x*f.x + wv.y*f.y + wv.z*f.z + wv.w*f.w;
        }
    }
    const float SC = 1.0507009873554805f, AL = 1.6732632423543772f;
    #pragma unroll
    for (int p = 0; p < NP; ++p) {
        float v = acc[p];
        acc[p] = v > 0.f ? SC*v : SC*AL*expm1f(v);
    }
    if (!FUSED) {
        // G layout: [keypoint][p*128 + c]  (K = 1024 inner dim, matches agg_w)
        #pragma unroll
        for (int p = 0; p < NP; ++p)
            dst[(size_t)bid*(NP*C_) + p*C_ + c] = acc[p];
    } else {
        #pragma unroll
        for (int p = 0; p < NP; ++p) gL[p*C_ + c] = acc[p];
        __syncthreads();
        float d_acc = 0.f;
        for (int pc = 0; pc < NP*C_; ++pc)
            d_acc += gL[pc] * agg_w[(size_t)pc*C_ + c];
        dst[(size_t)bid*C_ + c] = d_acc;   // unnormalized descriptor
    }
}

// ------------- K3: GEMM  G (8192x1024) @ agg_w (1024x128) -> raw descs ------
__global__ __launch_bounds__(256) void k_gemm(const float* __restrict__ G2,
        const float* __restrict__ A, float* __restrict__ out) {
    __shared__ __align__(16) float Gl[64*17];
    __shared__ __align__(16) float Al[16*128];
    int tid = threadIdx.x;
    int tx = tid & 31;       // col group: cols 4*tx..4*tx+3
    int ty = tid >> 5;       // 0..7 row group: rows 8*ty..8*ty+7
    int row0 = blockIdx.x * 64;
    float acc[8][4];
    #pragma unroll
    for (int r = 0; r < 8; ++r)
        #pragma unroll
        for (int j = 0; j < 4; ++j) acc[r][j] = 0.f;

    for (int kt = 0; kt < 1024/16; ++kt) {
        __syncthreads();
        for (int e = tid; e < 64*16; e += 256) {
            int r = e >> 4, kk = e & 15;
            Gl[r*17 + kk] = G2[(size_t)(row0 + r)*1024 + kt*16 + kk];
        }
        for (int e = tid; e < 16*128; e += 256) {
            int kk = e >> 7, d = e & 127;
            Al[kk*128 + d] = A[(size_t)(kt*16 + kk)*128 + d];
        }
        __syncthreads();
        #pragma unroll
        for (int kk = 0; kk < 16; ++kk) {
            float4 bv = *(const float4*)&Al[kk*128 + tx*4];
            #pragma unroll
            for (int r = 0; r < 8; ++r) {
                float a = Gl[(ty*8 + r)*17 + kk];
                acc[r][0] += a*bv.x; acc[r][1] += a*bv.y;
                acc[r][2] += a*bv.z; acc[r][3] += a*bv.w;
            }
        }
    }
    #pragma unroll
    for (int r = 0; r < 8; ++r) {
        float4 v; v.x = acc[r][0]; v.y = acc[r][1]; v.z = acc[r][2]; v.w = acc[r][3];
        *(float4*)&out[(size_t)(row0 + ty*8 + r)*128 + tx*4] = v;
    }
}

// ------------- K4: L2-normalize each 128-d descriptor in place -------------
__global__ __launch_bounds__(64) void k_norm(float* __restrict__ out) {
    int row = blockIdx.x;
    int l = threadIdx.x;
    float* r = out + (size_t)row*C_;
    float a = r[l], b = r[l+64];
    float ss = a*a + b*b;
    #pragma unroll
    for (int m = 1; m < 64; m <<= 1) ss += __shfl_xor(ss, m);
    float s = fmaxf(sqrtf(ss), 1e-12f);
    r[l] = a/s; r[l+64] = b/s;
}

extern "C" void kernel_launch(void* const* d_in, const int* in_sizes, int n_in,
                              void* d_out, int out_size, void* d_ws, size_t ws_size,
                              hipStream_t stream) {
    const float* x    = (const float*)d_in[0];
    const float* kpts = (const float*)d_in[1];
    const float* W1   = (const float*)d_in[2];
    const float* b1   = (const float*)d_in[3];
    const float* W2   = (const float*)d_in[4];
    const float* b2   = (const float*)d_in[5];
    const float* sfw  = (const float*)d_in[6];
    const float* aggw = (const float*)d_in[7];
    float* out_desc = (float*)d_out;                        // B*NK*C
    float* out_off  = out_desc + (size_t)B_*NK*C_;          // B*NK*NP*2

    char* ws = (char*)d_ws;
    float* pos = (float*)ws;                                // 512 KB
    const size_t G2_OFF   = (size_t)1 << 20;                // 1 MB
    const size_t G2_BYTES = (size_t)B_*NK*NP*C_*sizeof(float);   // 32 MB
    const size_t XT_OFF   = (size_t)1 << 26;                // 64 MB
    const size_t XT_BYTES = (size_t)B_*H_*W_*C_*sizeof(float);   // 128 MB
    bool useXT = ws_size >= XT_OFF + XT_BYTES;
    bool useG2 = ws_size >= G2_OFF + G2_BYTES;
    float* xt = (float*)(ws + XT_OFF);
    float* g2 = (float*)(ws + G2_OFF);

    if (useXT) {
        k_transpose<<<B_*H_*(C_/32)*(W_/32), 256, 0, stream>>>(x, xt);
        k_offsets<true><<<B_*NK, 64, 0, stream>>>(xt, kpts, W1, b1, W2, b2, out_off, pos);
        if (useG2) {
            k_sample<true,false><<<B_*NK, 128, 0, stream>>>(xt, pos, sfw, aggw, g2);
            k_gemm<<<B_*NK/64, 256, 0, stream>>>(g2, aggw, out_desc);
        } else {
            k_sample<true,true><<<B_*NK, 128, 0, stream>>>(xt, pos, sfw, aggw, out_desc);
        }
    } else {
        k_offsets<false><<<B_*NK, 64, 0, stream>>>(x, kpts, W1, b1, W2, b2, out_off, pos);
        if (useG2) {
            k_sample<false,false><<<B_*NK, 128, 0, stream>>>(x, pos, sfw, aggw, g2);
            k_gemm<<<B_*NK/64, 256, 0, stream>>>(g2, aggw, out_desc);
        } else {
            k_sample<false,true><<<B_*NK, 128, 0, stream>>>(x, pos, sfw, aggw, out_desc);
        }
    }
    k_norm<<<B_*NK, 64, 0, stream>>>(out_desc);
}

// Round 2
// 280.124 us; speedup vs baseline: 1.4575x; 1.4575x over previous
//
#include <hip/hip_runtime.h>
#include <math.h>

#define B_ 4
#define C_ 128
#define H_ 256
#define W_ 256
#define NK 2048
#define NP 8
#define HW_ (H_*W_)
#define MAXOFF 64.0f
#define NROWS (B_*NK)          // 8192
#define KSPLIT 4

// ---------------- K0: transpose x (B,C,H,W) -> xt (B,H,W,C) ----------------
__global__ __launch_bounds__(256) void k_transpose(const float* __restrict__ x,
                                                   float* __restrict__ xt) {
    __shared__ float tile[32][33];
    int bid = blockIdx.x;
    int xb = bid & 7;  bid >>= 3;   // W/32 = 8
    int cb = bid & 3;  bid >>= 2;   // C/32 = 4
    int y  = bid & 255; bid >>= 8;  // H
    int i  = bid;                   // B
    int tx  = threadIdx.x & 31;
    int ty0 = threadIdx.x >> 5;     // 0..7
    const float* src = x + ((size_t)(i*C_ + cb*32)*H_ + y)*W_ + xb*32;
    #pragma unroll
    for (int k = 0; k < 4; ++k) {
        int c = ty0 + k*8;
        tile[c][tx] = src[(size_t)c*HW_ + tx];
    }
    __syncthreads();
    float* dst = xt + ((size_t)(i*H_ + y)*W_ + xb*32)*C_ + cb*32;
    #pragma unroll
    for (int k = 0; k < 4; ++k) {
        int xo = ty0 + k*8;
        dst[(size_t)xo*C_ + tx] = tile[tx][xo];
    }
}

// ---------------- K1: per-keypoint patch conv + MLP -> offsets & positions --
template<bool XT>
__global__ __launch_bounds__(64) void k_offsets(const float* __restrict__ xin,
        const float* __restrict__ kpts, const float* __restrict__ W1,
        const float* __restrict__ b1, const float* __restrict__ W2,
        const float* __restrict__ b2, float* __restrict__ out_off,
        float* __restrict__ pos) {
    __shared__ float pL[1152];   // [a][b][c]
    __shared__ float hL[16];
    __shared__ float oL[16];
    int bid = blockIdx.x;            // = i*NK + n
    int i = bid >> 11;
    int t = threadIdx.x;

    float kx = kpts[(size_t)bid*2 + 0];
    float ky = kpts[(size_t)bid*2 + 1];
    float kwhx = (kx*0.5f + 0.5f) * (float)(W_-1);
    float kwhy = (ky*0.5f + 0.5f) * (float)(H_-1);
    int cx = (int)kwhx - 1; cx = cx < 0 ? 0 : (cx > 252 ? 252 : cx);
    int cy = (int)kwhy - 1; cy = cy < 0 ? 0 : (cy > 252 ? 252 : cy);

    if (XT) {
        #pragma unroll
        for (int a = 0; a < 3; ++a) {
            const float* src = xin + ((size_t)(i*H_ + cy + a)*W_ + cx)*C_;
            for (int j = t; j < 384; j += 64) pL[a*384 + j] = src[j];
        }
    } else {
        for (int e = t; e < 1152; e += 64) {
            int a = e/384; int r = e - a*384; int b = r >> 7; int c = r & 127;
            pL[e] = xin[(((size_t)(i*C_ + c))*H_ + cy + a)*W_ + cx + b];
        }
    }
    __syncthreads();

    int o = t & 15;
    int chunk = t >> 4;              // 0..3
    float partial = 0.f;
    const float* w1r = W1 + o*1152;  // layout [o][c][a][b]
    for (int c = chunk*32; c < chunk*32 + 32; ++c) {
        #pragma unroll
        for (int ab = 0; ab < 9; ++ab) {
            const int a = ab/3, b = ab - (ab/3)*3;
            partial += w1r[c*9 + ab] * pL[a*384 + b*128 + c];
        }
    }
    partial += __shfl_xor(partial, 16);
    partial += __shfl_xor(partial, 32);
    float h1 = fmaxf(partial + b1[o], 0.f);
    if (t < 16) hL[t] = h1;
    __syncthreads();
    if (t < 16) {
        float acc = b2[t];
        const float* w2r = W2 + t*16;
        #pragma unroll
        for (int oo = 0; oo < 16; ++oo) acc += w2r[oo]*hL[oo];
        acc = fminf(fmaxf(acc, -MAXOFF), MAXOFF);
        oL[t] = acc;
    }
    __syncthreads();
    if (t < 8) {
        float ox = oL[t], oy = oL[8 + t];
        size_t base = ((size_t)bid*NP + t)*2;
        out_off[base]   = ox;
        out_off[base+1] = oy;
        pos[base]   = kwhx + ox;
        pos[base+1] = kwhy + oy;
    }
}

// ------------- K2: bilinear gather + sf_w matmul + SELU (+opt fused agg) ----
template<bool XT, bool FUSED>
__global__ __launch_bounds__(128) void k_sample(const float* __restrict__ xin,
        const float* __restrict__ pos, const float* __restrict__ sf_w,
        const float* __restrict__ agg_w, float* __restrict__ dst) {
    __shared__ __align__(16) float featL[NP*C_];
    __shared__ float pp[16];
    int bid = blockIdx.x;           // keypoint global index
    int i = bid >> 11;
    int c = threadIdx.x;            // 0..127
    if (c < 16) pp[c] = pos[(size_t)bid*16 + c];
    __syncthreads();

    #pragma unroll
    for (int p = 0; p < NP; ++p) {
        float px = pp[p*2], py = pp[p*2+1];
        float x0f = floorf(px), y0f = floorf(py);
        int x0 = (int)x0f, y0 = (int)y0f;
        float wx1 = px - x0f, wy1 = py - y0f;
        float wx0 = 1.f - wx1, wy0 = 1.f - wy1;
        float acc = 0.f;
        #pragma unroll
        for (int tap = 0; tap < 4; ++tap) {
            int xi = x0 + (tap & 1);
            int yi = y0 + (tap >> 1);
            float w = ((tap & 1) ? wx1 : wx0) * ((tap >> 1) ? wy1 : wy0);
            bool valid = (xi >= 0) & (xi < W_) & (yi >= 0) & (yi < H_);
            int xc = min(max(xi, 0), W_-1);
            int yc = min(max(yi, 0), H_-1);
            float v;
            if (XT) v = xin[((size_t)(i*H_ + yc)*W_ + xc)*C_ + c];
            else    v = xin[(((size_t)(i*C_ + c))*H_ + yc)*W_ + xc];
            acc += (valid ? w : 0.f) * v;
        }
        featL[p*C_ + c] = acc;
    }
    __syncthreads();

    // sf transform: thread c plays role of output channel o
    float acc[NP];
    #pragma unroll
    for (int p = 0; p < NP; ++p) acc[p] = 0.f;
    const float4* sfr = (const float4*)(sf_w + (size_t)c*C_);
    const float4* fL4 = (const float4*)featL;
    for (int c4 = 0; c4 < C_/4; ++c4) {
        float4 wv = sfr[c4];
        #pragma unroll
        for (int p = 0; p < NP; ++p) {
            float4 f = fL4[p*(C_/4) + c4];
            acc[p] += wv.x*f.x + wv.y*f.y + wv.z*f.z + wv.w*f.w;
        }
    }
    const float SC = 1.0507009873554805f, AL = 1.6732632423543772f;
    #pragma unroll
    for (int p = 0; p < NP; ++p) {
        float v = acc[p];
        acc[p] = v > 0.f ? SC*v : SC*AL*expm1f(v);
    }
    if (!FUSED) {
        // G layout: [keypoint][p*128 + c]  (K = 1024 inner dim, matches agg_w)
        #pragma unroll
        for (int p = 0; p < NP; ++p)
            dst[(size_t)bid*(NP*C_) + p*C_ + c] = acc[p];
    } else {
        __shared__ __align__(16) float gL[NP*C_];
        #pragma unroll
        for (int p = 0; p < NP; ++p) gL[p*C_ + c] = acc[p];
        __syncthreads();
        float d_acc = 0.f;
        for (int pc = 0; pc < NP*C_; ++pc)
            d_acc += gL[pc] * agg_w[(size_t)pc*C_ + c];
        dst[(size_t)bid*C_ + c] = d_acc;   // unnormalized descriptor
    }
}

// ---- K3: split-K GEMM  G (8192x1024) @ agg_w (1024x128) -> partials --------
// grid = 128 row-tiles * KSPLIT; block 256. Each block: 64 rows, K-chunk 256.
// B (agg_w) read direct from global (512 KB, L2-resident) - no LDS staging.
#define GSTR 20   // LDS row stride in floats: keeps float4 writes 16B-aligned
__global__ __launch_bounds__(256) void k_gemm_split(const float* __restrict__ G2,
        const float* __restrict__ A, float* __restrict__ part) {
    __shared__ __align__(16) float Gl[64*GSTR];
    int bid = blockIdx.x;
    int ks = bid & (KSPLIT-1);
    int rt = bid >> 2;
    int tid = threadIdx.x;
    int tx = tid & 31;      // cols 4*tx..4*tx+3
    int ty = tid >> 5;      // rows 8*ty..8*ty+7
    int row0 = rt*64;
    int k0 = ks*(1024/KSPLIT);
    float acc[8][4];
    #pragma unroll
    for (int r = 0; r < 8; ++r) { acc[r][0]=acc[r][1]=acc[r][2]=acc[r][3]=0.f; }

    for (int kt = 0; kt < (1024/KSPLIT)/16; ++kt) {     // 16 iterations
        __syncthreads();
        {   // stage 64x16 G tile: one float4 per thread, aligned (GSTR%4==0)
            int r = tid >> 2, k4 = tid & 3;
            float4 g = *(const float4*)&G2[(size_t)(row0 + r)*1024 + k0 + kt*16 + k4*4];
            *(float4*)&Gl[r*GSTR + k4*4] = g;
        }
        __syncthreads();
        const float* Bp = A + (size_t)(k0 + kt*16)*128 + tx*4;
        #pragma unroll
        for (int kk = 0; kk < 16; ++kk) {
            float4 bv = *(const float4*)(Bp + (size_t)kk*128);
            #pragma unroll
            for (int r = 0; r < 8; ++r) {
                float a = Gl[(ty*8 + r)*GSTR + kk];
                acc[r][0] += a*bv.x; acc[r][1] += a*bv.y;
                acc[r][2] += a*bv.z; acc[r][3] += a*bv.w;
            }
        }
    }
    float* dst = part + ((size_t)ks*NROWS + row0)*128;
    #pragma unroll
    for (int r = 0; r < 8; ++r) {
        float4 v; v.x=acc[r][0]; v.y=acc[r][1]; v.z=acc[r][2]; v.w=acc[r][3];
        *(float4*)&dst[(size_t)(ty*8 + r)*128 + tx*4] = v;
    }
}

// ---- K4: reduce split-K partials + L2-normalize -> final descriptors -------
__global__ __launch_bounds__(128) void k_reduce_norm(const float* __restrict__ part,
                                                     float* __restrict__ out) {
    int row = blockIdx.x;
    int c = threadIdx.x;
    float v = 0.f;
    #pragma unroll
    for (int ks = 0; ks < KSPLIT; ++ks)
        v += part[((size_t)ks*NROWS + row)*128 + c];
    float ss = v*v;
    #pragma unroll
    for (int m = 1; m < 64; m <<= 1) ss += __shfl_xor(ss, m);
    __shared__ float s2[2];
    if ((c & 63) == 0) s2[c >> 6] = ss;
    __syncthreads();
    float s = fmaxf(sqrtf(s2[0] + s2[1]), 1e-12f);
    out[(size_t)row*128 + c] = v / s;
}

// ------------- K5: standalone L2-normalize (fallback paths) ----------------
__global__ __launch_bounds__(64) void k_norm(float* __restrict__ out) {
    int row = blockIdx.x;
    int l = threadIdx.x;
    float* r = out + (size_t)row*C_;
    float a = r[l], b = r[l+64];
    float ss = a*a + b*b;
    #pragma unroll
    for (int m = 1; m < 64; m <<= 1) ss += __shfl_xor(ss, m);
    float s = fmaxf(sqrtf(ss), 1e-12f);
    r[l] = a/s; r[l+64] = b/s;
}

extern "C" void kernel_launch(void* const* d_in, const int* in_sizes, int n_in,
                              void* d_out, int out_size, void* d_ws, size_t ws_size,
                              hipStream_t stream) {
    const float* x    = (const float*)d_in[0];
    const float* kpts = (const float*)d_in[1];
    const float* W1   = (const float*)d_in[2];
    const float* b1   = (const float*)d_in[3];
    const float* W2   = (const float*)d_in[4];
    const float* b2   = (const float*)d_in[5];
    const float* sfw  = (const float*)d_in[6];
    const float* aggw = (const float*)d_in[7];
    float* out_desc = (float*)d_out;                        // B*NK*C
    float* out_off  = out_desc + (size_t)B_*NK*C_;          // B*NK*NP*2

    char* ws = (char*)d_ws;
    float* pos = (float*)ws;                                     // 512 KB
    const size_t G2_OFF    = (size_t)1 << 20;                    // 1 MB
    const size_t G2_BYTES  = (size_t)NROWS*NP*C_*sizeof(float);  // 32 MB
    const size_t PART_OFF  = (size_t)34 << 20;                   // 34 MB
    const size_t PART_BYTES= (size_t)KSPLIT*NROWS*C_*sizeof(float); // 16 MB
    const size_t XT_OFF    = (size_t)1 << 26;                    // 64 MB
    const size_t XT_BYTES  = (size_t)B_*H_*W_*C_*sizeof(float);  // 128 MB
    bool useXT = ws_size >= XT_OFF + XT_BYTES;
    bool useG2 = ws_size >= PART_OFF + PART_BYTES;
    float* xt   = (float*)(ws + XT_OFF);
    float* g2   = (float*)(ws + G2_OFF);
    float* part = (float*)(ws + PART_OFF);

    if (useXT) {
        k_transpose<<<B_*H_*(C_/32)*(W_/32), 256, 0, stream>>>(x, xt);
        k_offsets<true><<<B_*NK, 64, 0, stream>>>(xt, kpts, W1, b1, W2, b2, out_off, pos);
        if (useG2) {
            k_sample<true,false><<<B_*NK, 128, 0, stream>>>(xt, pos, sfw, aggw, g2);
            k_gemm_split<<<(NROWS/64)*KSPLIT, 256, 0, stream>>>(g2, aggw, part);
            k_reduce_norm<<<NROWS, 128, 0, stream>>>(part, out_desc);
        } else {
            k_sample<true,true><<<B_*NK, 128, 0, stream>>>(xt, pos, sfw, aggw, out_desc);
            k_norm<<<B_*NK, 64, 0, stream>>>(out_desc);
        }
    } else {
        k_offsets<false><<<B_*NK, 64, 0, stream>>>(x, kpts, W1, b1, W2, b2, out_off, pos);
        if (useG2) {
            k_sample<false,false><<<B_*NK, 128, 0, stream>>>(x, pos, sfw, aggw, g2);
            k_gemm_split<<<(NROWS/64)*KSPLIT, 256, 0, stream>>>(g2, aggw, part);
            k_reduce_norm<<<NROWS, 128, 0, stream>>>(part, out_desc);
        } else {
            k_sample<false,true><<<B_*NK, 128, 0, stream>>>(x, pos, sfw, aggw, out_desc);
            k_norm<<<B_*NK, 64, 0, stream>>>(out_desc);
        }
    }
}

// Round 3
// 165.023 us; speedup vs baseline: 2.4741x; 1.6975x over previous
//
#include <hip/hip_runtime.h>
#include <hip/hip_bf16.h>
#include <math.h>

#define B_ 4
#define C_ 128
#define H_ 256
#define W_ 256
#define NK 2048
#define NP 8
#define HW_ (H_*W_)
#define MAXOFF 64.0f
#define NROWS (B_*NK)          // 8192
#define KSPLIT 4

typedef short s16x8 __attribute__((ext_vector_type(8)));
typedef float f32x4 __attribute__((ext_vector_type(4)));

__device__ inline float ldf(const float* p) { return *p; }
__device__ inline float ldf(const __hip_bfloat16* p) { return __bfloat162float(*p); }

// ---------------- K0: transpose x (B,C,H,W) fp32 -> xt (B,H,W,C) bf16 -------
__global__ __launch_bounds__(256) void k_transpose_bf(const float* __restrict__ x,
                                                      __hip_bfloat16* __restrict__ xt) {
    __shared__ float tile[32][33];
    int bid = blockIdx.x;
    int xb = bid & 7;  bid >>= 3;   // W/32 = 8
    int cb = bid & 3;  bid >>= 2;   // C/32 = 4
    int y  = bid & 255; bid >>= 8;  // H
    int i  = bid;                   // B
    int tx  = threadIdx.x & 31;
    int ty0 = threadIdx.x >> 5;     // 0..7
    const float* src = x + ((size_t)(i*C_ + cb*32)*H_ + y)*W_ + xb*32;
    #pragma unroll
    for (int k = 0; k < 4; ++k) {
        int c = ty0 + k*8;
        tile[c][tx] = src[(size_t)c*HW_ + tx];
    }
    __syncthreads();
    int tx2 = threadIdx.x & 15;     // channel pair
    int xo8 = threadIdx.x >> 4;     // 0..15
    __hip_bfloat16* dst = xt + ((size_t)(i*H_ + y)*W_ + xb*32)*C_ + cb*32;
    #pragma unroll
    for (int k = 0; k < 2; ++k) {
        int xo = xo8 + k*16;
        __hip_bfloat162 v;
        v.x = __float2bfloat16(tile[tx2*2][xo]);
        v.y = __float2bfloat16(tile[tx2*2+1][xo]);
        *(__hip_bfloat162*)(dst + (size_t)xo*C_ + tx2*2) = v;
    }
}

// -------- prep: W1 [o][c][a][b] fp32 -> W1b [o][e] bf16, e = (a*3+b)*128+c --
__global__ __launch_bounds__(256) void k_prep_w1(const float* __restrict__ W1,
                                                 __hip_bfloat16* __restrict__ W1b) {
    int t = blockIdx.x*256 + threadIdx.x;
    if (t >= 16*1152) return;
    int o = t / 1152, r = t % 1152;
    int ab = r >> 7, c = r & 127;
    W1b[t] = __float2bfloat16(W1[o*1152 + c*9 + ab]);
}

// ------ K1 (MFMA): 16 keypoints/block patch-conv + MLP -> offsets & pos -----
// P (16x1152) @ W1b^T (1152x16) via 36x mfma_f32_16x16x32_bf16, K-split 4 waves
#define PSTRB 2320   // LDS row stride bytes (1152*2 + 16): 16B aligned, 2-way
__global__ __launch_bounds__(256) void k_offsets_mfma(
        const __hip_bfloat16* __restrict__ xtb, const float* __restrict__ kpts,
        const __hip_bfloat16* __restrict__ W1b, const float* __restrict__ b1,
        const float* __restrict__ W2, const float* __restrict__ b2,
        float* __restrict__ out_off, float* __restrict__ pos) {
    __shared__ __align__(16) __hip_bfloat16 Pl[16*PSTRB/2];
    __shared__ __align__(16) __hip_bfloat16 W1l[16*PSTRB/2];
    __shared__ float Cp[4][16][17];
    __shared__ float hL[16][17];
    __shared__ float W2s[16*17];
    __shared__ float kwx[16], kwy[16];
    __shared__ int   kcx[16], kcy[16];

    int t = threadIdx.x;
    int blk = blockIdx.x;
    int i = blk >> 7;                 // 128 blocks per image

    if (t < 16) {
        int gk = blk*16 + t;
        float kx = kpts[(size_t)gk*2], ky = kpts[(size_t)gk*2 + 1];
        float wx = (kx*0.5f + 0.5f) * (float)(W_-1);
        float wy = (ky*0.5f + 0.5f) * (float)(H_-1);
        int cx = (int)wx - 1; cx = min(max(cx, 0), W_-1-3);
        int cy = (int)wy - 1; cy = min(max(cy, 0), H_-1-3);
        kwx[t] = wx; kwy[t] = wy; kcx[t] = cx; kcy[t] = cy;
    }
    W2s[(t>>4)*17 + (t&15)] = W2[t];
    {   // stage W1b -> W1l (row o = t>>4, 16 threads x 9 float4 per row)
        int o = t >> 4, l16 = t & 15;
        const float4* src = (const float4*)(W1b + (size_t)o*1152);
        #pragma unroll
        for (int j = 0; j < 9; ++j) {
            int f4 = l16 + j*16;
            *(float4*)((char*)W1l + o*PSTRB + f4*16) = src[f4];
        }
    }
    __syncthreads();
    {   // stage patches: thread group (t>>4)=kp, 9 row-segments of 256B
        int kp = t >> 4, l16 = t & 15;
        int cx = kcx[kp], cy = kcy[kp];
        #pragma unroll
        for (int j = 0; j < 9; ++j) {        // ab = j, a=j/3, b=j%3
            int a = j/3, b = j - (j/3)*3;
            const char* src = (const char*)(xtb + ((size_t)((i*H_ + cy + a)*W_ + cx + b))*C_);
            float4 v = *(const float4*)(src + l16*16);
            *(float4*)((char*)Pl + kp*PSTRB + j*256 + l16*16) = v;
        }
    }
    __syncthreads();
    {   // MFMA: wave w handles k-steps 9w..9w+8
        int w = t >> 6, l = t & 63;
        int r16 = l & 15, kq = l >> 4;
        const char* pA = (const char*)Pl  + r16*PSTRB + kq*16;
        const char* pB = (const char*)W1l + r16*PSTRB + kq*16;
        f32x4 acc = {0.f, 0.f, 0.f, 0.f};
        #pragma unroll
        for (int s = 0; s < 9; ++s) {
            int ks = w*9 + s;
            s16x8 af = *(const s16x8*)(pA + ks*64);
            s16x8 bf = *(const s16x8*)(pB + ks*64);
            acc = __builtin_amdgcn_mfma_f32_16x16x32_bf16(af, bf, acc, 0, 0, 0);
        }
        #pragma unroll
        for (int r = 0; r < 4; ++r)
            Cp[w][kq*4 + r][r16] = acc[r];
    }
    __syncthreads();
    int kp = t >> 4, o = t & 15;
    float sum = Cp[0][kp][o] + Cp[1][kp][o] + Cp[2][kp][o] + Cp[3][kp][o];
    hL[kp][o] = fmaxf(sum + b1[o], 0.f);
    __syncthreads();
    float acc2 = b2[o];
    #pragma unroll
    for (int oo = 0; oo < 16; ++oo)
        acc2 += hL[kp][oo] * W2s[o*17 + oo];
    acc2 = fminf(fmaxf(acc2, -MAXOFF), MAXOFF);
    int d = o >> 3, p = o & 7;
    int gk = blk*16 + kp;
    size_t base = ((size_t)gk*NP + p)*2 + d;
    out_off[base] = acc2;
    pos[base] = (d ? kwy[kp] : kwx[kp]) + acc2;
}

// -------- K1 fallback (fp32, no xt): original per-keypoint version ----------
__global__ __launch_bounds__(64) void k_offsets_f32(const float* __restrict__ xin,
        const float* __restrict__ kpts, const float* __restrict__ W1,
        const float* __restrict__ b1, const float* __restrict__ W2,
        const float* __restrict__ b2, float* __restrict__ out_off,
        float* __restrict__ pos) {
    __shared__ float pL[1152];
    __shared__ float hL2[16];
    __shared__ float oL[16];
    int bid = blockIdx.x;
    int i = bid >> 11;
    int t = threadIdx.x;
    float kx = kpts[(size_t)bid*2 + 0];
    float ky = kpts[(size_t)bid*2 + 1];
    float kwhx = (kx*0.5f + 0.5f) * (float)(W_-1);
    float kwhy = (ky*0.5f + 0.5f) * (float)(H_-1);
    int cx = (int)kwhx - 1; cx = cx < 0 ? 0 : (cx > 252 ? 252 : cx);
    int cy = (int)kwhy - 1; cy = cy < 0 ? 0 : (cy > 252 ? 252 : cy);
    for (int e = t; e < 1152; e += 64) {
        int a = e/384; int r = e - a*384; int b = r >> 7; int c = r & 127;
        pL[e] = xin[(((size_t)(i*C_ + c))*H_ + cy + a)*W_ + cx + b];
    }
    __syncthreads();
    int o = t & 15;
    int chunk = t >> 4;
    float partial = 0.f;
    const float* w1r = W1 + o*1152;
    for (int c = chunk*32; c < chunk*32 + 32; ++c) {
        #pragma unroll
        for (int ab = 0; ab < 9; ++ab) {
            const int a = ab/3, b = ab - (ab/3)*3;
            partial += w1r[c*9 + ab] * pL[a*384 + b*128 + c];
        }
    }
    partial += __shfl_xor(partial, 16);
    partial += __shfl_xor(partial, 32);
    float h1 = fmaxf(partial + b1[o], 0.f);
    if (t < 16) hL2[t] = h1;
    __syncthreads();
    if (t < 16) {
        float acc = b2[t];
        const float* w2r = W2 + t*16;
        #pragma unroll
        for (int oo = 0; oo < 16; ++oo) acc += w2r[oo]*hL2[oo];
        acc = fminf(fmaxf(acc, -MAXOFF), MAXOFF);
        oL[t] = acc;
    }
    __syncthreads();
    if (t < 8) {
        float ox = oL[t], oy = oL[8 + t];
        size_t base = ((size_t)bid*NP + t)*2;
        out_off[base]   = ox;
        out_off[base+1] = oy;
        pos[base]   = kwhx + ox;
        pos[base+1] = kwhy + oy;
    }
}

// ------------- K2: bilinear gather + sf_w matmul + SELU ---------------------
template<bool XT, bool FUSED, typename T>
__global__ __launch_bounds__(128) void k_sample(const T* __restrict__ xin,
        const float* __restrict__ pos, const float* __restrict__ sf_w,
        const float* __restrict__ agg_w, float* __restrict__ dst) {
    __shared__ __align__(16) float featL[NP*C_];
    __shared__ float pp[16];
    int bid = blockIdx.x;
    int i = bid >> 11;
    int c = threadIdx.x;
    if (c < 16) pp[c] = pos[(size_t)bid*16 + c];
    __syncthreads();

    #pragma unroll
    for (int p = 0; p < NP; ++p) {
        float px = pp[p*2], py = pp[p*2+1];
        float x0f = floorf(px), y0f = floorf(py);
        int x0 = (int)x0f, y0 = (int)y0f;
        float wx1 = px - x0f, wy1 = py - y0f;
        float wx0 = 1.f - wx1, wy0 = 1.f - wy1;
        float acc = 0.f;
        #pragma unroll
        for (int tap = 0; tap < 4; ++tap) {
            int xi = x0 + (tap & 1);
            int yi = y0 + (tap >> 1);
            float w = ((tap & 1) ? wx1 : wx0) * ((tap >> 1) ? wy1 : wy0);
            bool valid = (xi >= 0) & (xi < W_) & (yi >= 0) & (yi < H_);
            int xc = min(max(xi, 0), W_-1);
            int yc = min(max(yi, 0), H_-1);
            float v;
            if (XT) v = ldf(&xin[((size_t)(i*H_ + yc)*W_ + xc)*C_ + c]);
            else    v = ldf(&xin[(((size_t)(i*C_ + c))*H_ + yc)*W_ + xc]);
            acc += (valid ? w : 0.f) * v;
        }
        featL[p*C_ + c] = acc;
    }
    __syncthreads();

    float acc[NP];
    #pragma unroll
    for (int p = 0; p < NP; ++p) acc[p] = 0.f;
    const float4* sfr = (const float4*)(sf_w + (size_t)c*C_);
    const float4* fL4 = (const float4*)featL;
    for (int c4 = 0; c4 < C_/4; ++c4) {
        float4 wv = sfr[c4];
        #pragma unroll
        for (int p = 0; p < NP; ++p) {
            float4 f = fL4[p*(C_/4) + c4];
            acc[p] += wv.x*f.x + wv.y*f.y + wv.z*f.z + wv.w*f.w;
        }
    }
    const float SC = 1.0507009873554805f, AL = 1.6732632423543772f;
    #pragma unroll
    for (int p = 0; p < NP; ++p) {
        float v = acc[p];
        acc[p] = v > 0.f ? SC*v : SC*AL*expm1f(v);
    }
    if (!FUSED) {
        #pragma unroll
        for (int p = 0; p < NP; ++p)
            dst[(size_t)bid*(NP*C_) + p*C_ + c] = acc[p];
    } else {
        __shared__ __align__(16) float gL[NP*C_];
        #pragma unroll
        for (int p = 0; p < NP; ++p) gL[p*C_ + c] = acc[p];
        __syncthreads();
        float d_acc = 0.f;
        for (int pc = 0; pc < NP*C_; ++pc)
            d_acc += gL[pc] * agg_w[(size_t)pc*C_ + c];
        dst[(size_t)bid*C_ + c] = d_acc;
    }
}

// ---- K3: split-K GEMM  G (8192x1024) @ agg_w (1024x128) -> partials --------
#define GSTR 20
__global__ __launch_bounds__(256) void k_gemm_split(const float* __restrict__ G2,
        const float* __restrict__ A, float* __restrict__ part) {
    __shared__ __align__(16) float Gl[64*GSTR];
    int bid = blockIdx.x;
    int ks = bid & (KSPLIT-1);
    int rt = bid >> 2;
    int tid = threadIdx.x;
    int tx = tid & 31;
    int ty = tid >> 5;
    int row0 = rt*64;
    int k0 = ks*(1024/KSPLIT);
    float acc[8][4];
    #pragma unroll
    for (int r = 0; r < 8; ++r) { acc[r][0]=acc[r][1]=acc[r][2]=acc[r][3]=0.f; }

    for (int kt = 0; kt < (1024/KSPLIT)/16; ++kt) {
        __syncthreads();
        {
            int r = tid >> 2, k4 = tid & 3;
            float4 g = *(const float4*)&G2[(size_t)(row0 + r)*1024 + k0 + kt*16 + k4*4];
            *(float4*)&Gl[r*GSTR + k4*4] = g;
        }
        __syncthreads();
        const float* Bp = A + (size_t)(k0 + kt*16)*128 + tx*4;
        #pragma unroll
        for (int kk = 0; kk < 16; ++kk) {
            float4 bv = *(const float4*)(Bp + (size_t)kk*128);
            #pragma unroll
            for (int r = 0; r < 8; ++r) {
                float a = Gl[(ty*8 + r)*GSTR + kk];
                acc[r][0] += a*bv.x; acc[r][1] += a*bv.y;
                acc[r][2] += a*bv.z; acc[r][3] += a*bv.w;
            }
        }
    }
    float* dst = part + ((size_t)ks*NROWS + row0)*128;
    #pragma unroll
    for (int r = 0; r < 8; ++r) {
        float4 v; v.x=acc[r][0]; v.y=acc[r][1]; v.z=acc[r][2]; v.w=acc[r][3];
        *(float4*)&dst[(size_t)(ty*8 + r)*128 + tx*4] = v;
    }
}

// ---- K4: reduce split-K partials + L2-normalize ----------------------------
__global__ __launch_bounds__(128) void k_reduce_norm(const float* __restrict__ part,
                                                     float* __restrict__ out) {
    int row = blockIdx.x;
    int c = threadIdx.x;
    float v = 0.f;
    #pragma unroll
    for (int ks = 0; ks < KSPLIT; ++ks)
        v += part[((size_t)ks*NROWS + row)*128 + c];
    float ss = v*v;
    #pragma unroll
    for (int m = 1; m < 64; m <<= 1) ss += __shfl_xor(ss, m);
    __shared__ float s2[2];
    if ((c & 63) == 0) s2[c >> 6] = ss;
    __syncthreads();
    float s = fmaxf(sqrtf(s2[0] + s2[1]), 1e-12f);
    out[(size_t)row*128 + c] = v / s;
}

// ------------- K5: standalone L2-normalize (fallback) -----------------------
__global__ __launch_bounds__(64) void k_norm(float* __restrict__ out) {
    int row = blockIdx.x;
    int l = threadIdx.x;
    float* r = out + (size_t)row*C_;
    float a = r[l], b = r[l+64];
    float ss = a*a + b*b;
    #pragma unroll
    for (int m = 1; m < 64; m <<= 1) ss += __shfl_xor(ss, m);
    float s = fmaxf(sqrtf(ss), 1e-12f);
    r[l] = a/s; r[l+64] = b/s;
}

extern "C" void kernel_launch(void* const* d_in, const int* in_sizes, int n_in,
                              void* d_out, int out_size, void* d_ws, size_t ws_size,
                              hipStream_t stream) {
    const float* x    = (const float*)d_in[0];
    const float* kpts = (const float*)d_in[1];
    const float* W1   = (const float*)d_in[2];
    const float* b1   = (const float*)d_in[3];
    const float* W2   = (const float*)d_in[4];
    const float* b2   = (const float*)d_in[5];
    const float* sfw  = (const float*)d_in[6];
    const float* aggw = (const float*)d_in[7];
    float* out_desc = (float*)d_out;
    float* out_off  = out_desc + (size_t)B_*NK*C_;

    char* ws = (char*)d_ws;
    float* pos = (float*)ws;                                        // 512 KB
    const size_t G2_OFF    = (size_t)1 << 20;                       // 1 MB
    const size_t PART_OFF  = (size_t)34 << 20;                      // 34 MB
    const size_t PART_BYTES= (size_t)KSPLIT*NROWS*C_*sizeof(float); // 16 MB
    const size_t W1B_OFF   = (size_t)50 << 20;                      // 50 MB
    const size_t XT_OFF    = (size_t)1 << 26;                       // 64 MB
    const size_t XT_BYTES  = (size_t)B_*H_*W_*C_*2;                 // 64 MB (bf16)
    bool useXT = ws_size >= XT_OFF + XT_BYTES;
    bool useG2 = ws_size >= PART_OFF + PART_BYTES;
    __hip_bfloat16* xtb = (__hip_bfloat16*)(ws + XT_OFF);
    __hip_bfloat16* w1b = (__hip_bfloat16*)(ws + W1B_OFF);
    float* g2   = (float*)(ws + G2_OFF);
    float* part = (float*)(ws + PART_OFF);

    if (useXT) {
        k_prep_w1<<<(16*1152 + 255)/256, 256, 0, stream>>>(W1, w1b);
        k_transpose_bf<<<B_*H_*(C_/32)*(W_/32), 256, 0, stream>>>(x, xtb);
        k_offsets_mfma<<<NROWS/16, 256, 0, stream>>>(xtb, kpts, w1b, b1, W2, b2, out_off, pos);
        if (useG2) {
            k_sample<true,false,__hip_bfloat16><<<B_*NK, 128, 0, stream>>>(xtb, pos, sfw, aggw, g2);
            k_gemm_split<<<(NROWS/64)*KSPLIT, 256, 0, stream>>>(g2, aggw, part);
            k_reduce_norm<<<NROWS, 128, 0, stream>>>(part, out_desc);
        } else {
            k_sample<true,true,__hip_bfloat16><<<B_*NK, 128, 0, stream>>>(xtb, pos, sfw, aggw, out_desc);
            k_norm<<<B_*NK, 64, 0, stream>>>(out_desc);
        }
    } else {
        k_offsets_f32<<<B_*NK, 64, 0, stream>>>(x, kpts, W1, b1, W2, b2, out_off, pos);
        if (useG2) {
            k_sample<false,false,float><<<B_*NK, 128, 0, stream>>>(x, pos, sfw, aggw, g2);
            k_gemm_split<<<(NROWS/64)*KSPLIT, 256, 0, stream>>>(g2, aggw, part);
            k_reduce_norm<<<NROWS, 128, 0, stream>>>(part, out_desc);
        } else {
            k_sample<false,true,float><<<B_*NK, 128, 0, stream>>>(x, pos, sfw, aggw, out_desc);
            k_norm<<<B_*NK, 64, 0, stream>>>(out_desc);
        }
    }
}

// Round 5
// 86.374 us; speedup vs baseline: 4.7268x; 1.9106x over previous
//
#include <hip/hip_runtime.h>
#include <hip/hip_bf16.h>
#include <math.h>

#define B_ 4
#define C_ 128
#define H_ 256
#define W_ 256
#define NK 2048
#define NP 8
#define HW_ (H_*W_)
#define MAXOFF 64.0f
#define NROWS (B_*NK)          // 8192

typedef short s16x8 __attribute__((ext_vector_type(8)));
typedef short s16x4 __attribute__((ext_vector_type(4)));
typedef float f32x4 __attribute__((ext_vector_type(4)));

#define SELU_SC 1.0507009873554805f
#define SELU_AL 1.6732632423543772f

__device__ inline float bf2f(short b) {
    union { unsigned int u; float f; } cv;
    cv.u = ((unsigned int)(unsigned short)b) << 16;
    return cv.f;
}
__device__ inline short f2bf_s(float f) {
    __hip_bfloat16 h = __float2bfloat16(f);
    return *(short*)&h;
}

// ---------------- K0: transpose x (B,C,H,W) fp32 -> xt (B,H,W,C) bf16 -------
__global__ __launch_bounds__(256) void k_transpose_bf(const float* __restrict__ x,
                                                      __hip_bfloat16* __restrict__ xt) {
    __shared__ float tile[32][33];
    int bid = blockIdx.x;
    int xb = bid & 7;  bid >>= 3;
    int cb = bid & 3;  bid >>= 2;
    int y  = bid & 255; bid >>= 8;
    int i  = bid;
    int tx  = threadIdx.x & 31;
    int ty0 = threadIdx.x >> 5;
    const float* src = x + ((size_t)(i*C_ + cb*32)*H_ + y)*W_ + xb*32;
    #pragma unroll
    for (int k = 0; k < 4; ++k) {
        int c = ty0 + k*8;
        tile[c][tx] = src[(size_t)c*HW_ + tx];
    }
    __syncthreads();
    int tx2 = threadIdx.x & 15;
    int xo8 = threadIdx.x >> 4;
    __hip_bfloat16* dst = xt + ((size_t)(i*H_ + y)*W_ + xb*32)*C_ + cb*32;
    #pragma unroll
    for (int k = 0; k < 2; ++k) {
        int xo = xo8 + k*16;
        __hip_bfloat162 v;
        v.x = __float2bfloat16(tile[tx2*2][xo]);
        v.y = __float2bfloat16(tile[tx2*2+1][xo]);
        *(__hip_bfloat162*)(dst + (size_t)xo*C_ + tx2*2) = v;
    }
}

// -------- prep: W1 [o][c][a][b] fp32 -> W1b [o][e] bf16, e = (a*3+b)*128+c --
__global__ __launch_bounds__(256) void k_prep_w1(const float* __restrict__ W1,
                                                 __hip_bfloat16* __restrict__ W1b) {
    int t = blockIdx.x*256 + threadIdx.x;
    if (t >= 16*1152) return;
    int o = t / 1152, r = t % 1152;
    int ab = r >> 7, c = r & 127;
    W1b[t] = __float2bfloat16(W1[o*1152 + c*9 + ab]);
}

// -------- prep: sf_w -> B-fragment-linearized bf16  [j][ks][l][e] -----------
// elem = sf_w[j*16 + (l&15)][ks*32 + (l>>4)*8 + e]
__global__ __launch_bounds__(256) void k_prep_sf(const float* __restrict__ sf_w,
                                                 __hip_bfloat16* __restrict__ sfb) {
    int t = blockIdx.x*256 + threadIdx.x;     // 0 .. 32767
    int e = t & 7, l = (t >> 3) & 63, ks = (t >> 9) & 3, j = t >> 11;
    sfb[t] = __float2bfloat16(sf_w[(j*16 + (l & 15))*128 + ks*32 + ((l >> 4) << 3) + e]);
}

// -------- prep: agg_w -> B-fragment-linearized bf16 [jd][p][ks][l][e] -------
// elem = agg_w[p][ks*32+(l>>4)*8+e][jd*16+(l&15)]
__global__ __launch_bounds__(256) void k_prep_agg(const float* __restrict__ agg_w,
                                                  __hip_bfloat16* __restrict__ aggb) {
    int t = blockIdx.x*256 + threadIdx.x;     // 0 .. 131071
    int e = t & 7, l = (t >> 3) & 63, ks = (t >> 9) & 3, p = (t >> 11) & 7, jd = t >> 14;
    aggb[t] = __float2bfloat16(agg_w[((size_t)p*128 + ks*32 + ((l >> 4) << 3) + e)*128 + jd*16 + (l & 15)]);
}

// ------ K1 (MFMA): 16 keypoints/block patch-conv + MLP -> offsets & pos -----
#define PSTRB 2320
__global__ __launch_bounds__(256) void k_offsets_mfma(
        const __hip_bfloat16* __restrict__ xtb, const float* __restrict__ kpts,
        const __hip_bfloat16* __restrict__ W1b, const float* __restrict__ b1,
        const float* __restrict__ W2, const float* __restrict__ b2,
        float* __restrict__ out_off, float* __restrict__ pos) {
    __shared__ __align__(16) __hip_bfloat16 Pl[16*PSTRB/2];
    __shared__ __align__(16) __hip_bfloat16 W1l[16*PSTRB/2];
    __shared__ float Cp[4][16][17];
    __shared__ float hL[16][17];
    __shared__ float W2s[16*17];
    __shared__ float kwx[16], kwy[16];
    __shared__ int   kcx[16], kcy[16];

    int t = threadIdx.x;
    int blk = blockIdx.x;
    int i = blk >> 7;

    if (t < 16) {
        int gk = blk*16 + t;
        float kx = kpts[(size_t)gk*2], ky = kpts[(size_t)gk*2 + 1];
        float wx = (kx*0.5f + 0.5f) * (float)(W_-1);
        float wy = (ky*0.5f + 0.5f) * (float)(H_-1);
        int cx = (int)wx - 1; cx = min(max(cx, 0), W_-1-3);
        int cy = (int)wy - 1; cy = min(max(cy, 0), H_-1-3);
        kwx[t] = wx; kwy[t] = wy; kcx[t] = cx; kcy[t] = cy;
    }
    W2s[(t>>4)*17 + (t&15)] = W2[t];
    {
        int o = t >> 4, l16 = t & 15;
        const float4* src = (const float4*)(W1b + (size_t)o*1152);
        #pragma unroll
        for (int j = 0; j < 9; ++j) {
            int f4 = l16 + j*16;
            *(float4*)((char*)W1l + o*PSTRB + f4*16) = src[f4];
        }
    }
    __syncthreads();
    {
        int kp = t >> 4, l16 = t & 15;
        int cx = kcx[kp], cy = kcy[kp];
        #pragma unroll
        for (int j = 0; j < 9; ++j) {
            int a = j/3, b = j - (j/3)*3;
            const char* src = (const char*)(xtb + ((size_t)((i*H_ + cy + a)*W_ + cx + b))*C_);
            float4 v = *(const float4*)(src + l16*16);
            *(float4*)((char*)Pl + kp*PSTRB + j*256 + l16*16) = v;
        }
    }
    __syncthreads();
    {
        int w = t >> 6, l = t & 63;
        int r16 = l & 15, kq = l >> 4;
        const char* pA = (const char*)Pl  + r16*PSTRB + kq*16;
        const char* pB = (const char*)W1l + r16*PSTRB + kq*16;
        f32x4 acc = {0.f, 0.f, 0.f, 0.f};
        #pragma unroll
        for (int s = 0; s < 9; ++s) {
            int ks = w*9 + s;
            s16x8 af = *(const s16x8*)(pA + ks*64);
            s16x8 bf = *(const s16x8*)(pB + ks*64);
            acc = __builtin_amdgcn_mfma_f32_16x16x32_bf16(af, bf, acc, 0, 0, 0);
        }
        #pragma unroll
        for (int r = 0; r < 4; ++r)
            Cp[w][kq*4 + r][r16] = acc[r];
    }
    __syncthreads();
    int kp = t >> 4, o = t & 15;
    float sum = Cp[0][kp][o] + Cp[1][kp][o] + Cp[2][kp][o] + Cp[3][kp][o];
    hL[kp][o] = fmaxf(sum + b1[o], 0.f);
    __syncthreads();
    float acc2 = b2[o];
    #pragma unroll
    for (int oo = 0; oo < 16; ++oo)
        acc2 += hL[kp][oo] * W2s[o*17 + oo];
    acc2 = fminf(fmaxf(acc2, -MAXOFF), MAXOFF);
    int d = o >> 3, p = o & 7;
    int gk = blk*16 + kp;
    size_t base = ((size_t)gk*NP + p)*2 + d;
    out_off[base] = acc2;
    pos[base] = (d ? kwy[kp] : kwx[kp]) + acc2;
}

// ------------- K2a: pure bilinear gather -> featb[n][p][c] bf16 -------------
__global__ __launch_bounds__(256) void k_gather(const __hip_bfloat16* __restrict__ xtb,
        const float* __restrict__ pos, __hip_bfloat16* __restrict__ featb) {
    __shared__ float pp[16];
    int kp = blockIdx.x;
    int i = kp >> 11;
    int t = threadIdx.x;
    if (t < 16) pp[t] = pos[(size_t)kp*16 + t];
    __syncthreads();
    int p = t >> 5, lane = t & 31;
    float px = pp[p*2], py = pp[p*2+1];
    float x0f = floorf(px), y0f = floorf(py);
    int x0 = (int)x0f, y0 = (int)y0f;
    float wx1 = px - x0f, wy1 = py - y0f;
    float wx0 = 1.f - wx1, wy0 = 1.f - wy1;
    int c0 = lane*4;
    float acc0 = 0.f, acc1 = 0.f, acc2 = 0.f, acc3 = 0.f;
    #pragma unroll
    for (int tap = 0; tap < 4; ++tap) {
        int xi = x0 + (tap & 1);
        int yi = y0 + (tap >> 1);
        float w = ((tap & 1) ? wx1 : wx0) * ((tap >> 1) ? wy1 : wy0);
        bool valid = (xi >= 0) & (xi < W_) & (yi >= 0) & (yi < H_);
        int xc = min(max(xi, 0), W_-1);
        int yc = min(max(yi, 0), H_-1);
        float wv = valid ? w : 0.f;
        const __hip_bfloat16* src = xtb + ((size_t)(i*H_ + yc)*W_ + xc)*C_ + c0;
        s16x4 v = *(const s16x4*)src;
        acc0 += wv * bf2f(v[0]);
        acc1 += wv * bf2f(v[1]);
        acc2 += wv * bf2f(v[2]);
        acc3 += wv * bf2f(v[3]);
    }
    s16x4 ov;
    ov[0] = f2bf_s(acc0); ov[1] = f2bf_s(acc1);
    ov[2] = f2bf_s(acc2); ov[3] = f2bf_s(acc3);
    *(s16x4*)(featb + ((size_t)kp*NP + p)*C_ + c0) = ov;
}

// ------------- K2b: fused MFMA tail: sf+SELU+agg -> raw descs ---------------
// block = 256 thr (4 waves), 16 keypoints; wave w owns positions {2w, 2w+1}
#define HSTR 136   // bf16 elems per Hl row (272 B): breaks 256B-stride conflicts
#define RSTR 132
__global__ __launch_bounds__(256) void k_tail(const __hip_bfloat16* __restrict__ featb,
        const __hip_bfloat16* __restrict__ sfb,   // [8][4][64][8]
        const __hip_bfloat16* __restrict__ aggb,  // [8][8][4][64][8]
        float* __restrict__ descs) {
    __shared__ __align__(16) __hip_bfloat16 Hl[4][16*HSTR];
    __shared__ float red[4][16][RSTR];
    int t = threadIdx.x;
    int w = t >> 6, l = t & 63;
    int r16 = l & 15, q = l >> 4;
    int kp0 = blockIdx.x * 16;

    f32x4 dacc[8];
    #pragma unroll
    for (int jd = 0; jd < 8; ++jd) dacc[jd] = (f32x4){0.f,0.f,0.f,0.f};

    #pragma unroll
    for (int pi = 0; pi < 2; ++pi) {
        int p = w*2 + pi;
        // A-fragments from featb: row kp0+r16, k=c
        const short* fbase = (const short*)featb + ((size_t)(kp0 + r16)*NP + p)*C_ + q*8;
        s16x8 af[4];
        #pragma unroll
        for (int ks = 0; ks < 4; ++ks) af[ks] = *(const s16x8*)(fbase + ks*32);
        // sf GEMM + SELU -> Hl
        #pragma unroll
        for (int j = 0; j < 8; ++j) {
            f32x4 acc = (f32x4){0.f,0.f,0.f,0.f};
            const short* sb = (const short*)sfb + ((j*4)*64 + l)*8;
            #pragma unroll
            for (int ks = 0; ks < 4; ++ks)
                acc = __builtin_amdgcn_mfma_f32_16x16x32_bf16(af[ks], *(const s16x8*)(sb + ks*512), acc, 0, 0, 0);
            #pragma unroll
            for (int r = 0; r < 4; ++r) {
                float v = acc[r];
                v = v > 0.f ? SELU_SC*v : SELU_SC*SELU_AL*expm1f(v);
                Hl[w][(q*4 + r)*HSTR + j*16 + r16] = __float2bfloat16(v);
            }
        }
        // agg GEMM: A-fragments from Hl (same wave wrote it)
        s16x8 ah[4];
        #pragma unroll
        for (int ks = 0; ks < 4; ++ks)
            ah[ks] = *(const s16x8*)&Hl[w][r16*HSTR + ks*32 + q*8];
        #pragma unroll
        for (int jd = 0; jd < 8; ++jd) {
            const short* ab = (const short*)aggb + (((jd*8 + p)*4)*64 + l)*8;
            #pragma unroll
            for (int ks = 0; ks < 4; ++ks)
                dacc[jd] = __builtin_amdgcn_mfma_f32_16x16x32_bf16(ah[ks], *(const s16x8*)(ab + ks*512), dacc[jd], 0, 0, 0);
        }
    }
    // cross-wave reduce (each wave holds partial over its 2 positions)
    #pragma unroll
    for (int jd = 0; jd < 8; ++jd)
        #pragma unroll
        for (int r = 0; r < 4; ++r)
            red[w][q*4 + r][jd*16 + r16] = dacc[jd][r];
    __syncthreads();
    for (int e = t; e < 16*128; e += 256) {
        int row = e >> 7, d = e & 127;
        float v = red[0][row][d] + red[1][row][d] + red[2][row][d] + red[3][row][d];
        descs[(size_t)(kp0 + row)*C_ + d] = v;
    }
}

// ------------- K4: L2-normalize each 128-d descriptor in place --------------
__global__ __launch_bounds__(64) void k_norm(float* __restrict__ out) {
    int row = blockIdx.x;
    int l = threadIdx.x;
    float* r = out + (size_t)row*C_;
    float a = r[l], b = r[l+64];
    float ss = a*a + b*b;
    #pragma unroll
    for (int m = 1; m < 64; m <<= 1) ss += __shfl_xor(ss, m);
    float s = fmaxf(sqrtf(ss), 1e-12f);
    r[l] = a/s; r[l+64] = b/s;
}

// ---------------- fallback path (no workspace): fp32 direct -----------------
__global__ __launch_bounds__(64) void k_offsets_f32(const float* __restrict__ xin,
        const float* __restrict__ kpts, const float* __restrict__ W1,
        const float* __restrict__ b1, const float* __restrict__ W2,
        const float* __restrict__ b2, float* __restrict__ out_off,
        float* __restrict__ pos) {
    __shared__ float pL[1152];
    __shared__ float hL2[16];
    __shared__ float oL[16];
    int bid = blockIdx.x;
    int i = bid >> 11;
    int t = threadIdx.x;
    float kx = kpts[(size_t)bid*2 + 0];
    float ky = kpts[(size_t)bid*2 + 1];
    float kwhx = (kx*0.5f + 0.5f) * (float)(W_-1);
    float kwhy = (ky*0.5f + 0.5f) * (float)(H_-1);
    int cx = (int)kwhx - 1; cx = cx < 0 ? 0 : (cx > 252 ? 252 : cx);
    int cy = (int)kwhy - 1; cy = cy < 0 ? 0 : (cy > 252 ? 252 : cy);
    for (int e = t; e < 1152; e += 64) {
        int a = e/384; int r = e - a*384; int b = r >> 7; int c = r & 127;
        pL[e] = xin[(((size_t)(i*C_ + c))*H_ + cy + a)*W_ + cx + b];
    }
    __syncthreads();
    int o = t & 15;
    int chunk = t >> 4;
    float partial = 0.f;
    const float* w1r = W1 + o*1152;
    for (int c = chunk*32; c < chunk*32 + 32; ++c) {
        #pragma unroll
        for (int ab = 0; ab < 9; ++ab) {
            const int a = ab/3, b = ab - (ab/3)*3;
            partial += w1r[c*9 + ab] * pL[a*384 + b*128 + c];
        }
    }
    partial += __shfl_xor(partial, 16);
    partial += __shfl_xor(partial, 32);
    float h1 = fmaxf(partial + b1[o], 0.f);
    if (t < 16) hL2[t] = h1;
    __syncthreads();
    if (t < 16) {
        float acc = b2[t];
        const float* w2r = W2 + t*16;
        #pragma unroll
        for (int oo = 0; oo < 16; ++oo) acc += w2r[oo]*hL2[oo];
        acc = fminf(fmaxf(acc, -MAXOFF), MAXOFF);
        oL[t] = acc;
    }
    __syncthreads();
    if (t < 8) {
        float ox = oL[t], oy = oL[8 + t];
        size_t base = ((size_t)bid*NP + t)*2;
        out_off[base]   = ox;
        out_off[base+1] = oy;
        pos[base]   = kwhx + ox;
        pos[base+1] = kwhy + oy;
    }
}

__global__ __launch_bounds__(128) void k_sample_f32(const float* __restrict__ xin,
        const float* __restrict__ pos, const float* __restrict__ sf_w,
        const float* __restrict__ agg_w, float* __restrict__ dst) {
    __shared__ __align__(16) float featL[NP*C_];
    __shared__ float pp[16];
    int bid = blockIdx.x;
    int i = bid >> 11;
    int c = threadIdx.x;
    if (c < 16) pp[c] = pos[(size_t)bid*16 + c];
    __syncthreads();
    #pragma unroll
    for (int p = 0; p < NP; ++p) {
        float px = pp[p*2], py = pp[p*2+1];
        float x0f = floorf(px), y0f = floorf(py);
        int x0 = (int)x0f, y0 = (int)y0f;
        float wx1 = px - x0f, wy1 = py - y0f;
        float wx0 = 1.f - wx1, wy0 = 1.f - wy1;
        float acc = 0.f;
        #pragma unroll
        for (int tap = 0; tap < 4; ++tap) {
            int xi = x0 + (tap & 1);
            int yi = y0 + (tap >> 1);
            float w = ((tap & 1) ? wx1 : wx0) * ((tap >> 1) ? wy1 : wy0);
            bool valid = (xi >= 0) & (xi < W_) & (yi >= 0) & (yi < H_);
            int xc = min(max(xi, 0), W_-1);
            int yc = min(max(yi, 0), H_-1);
            acc += (valid ? w : 0.f) * xin[(((size_t)(i*C_ + c))*H_ + yc)*W_ + xc];
        }
        featL[p*C_ + c] = acc;
    }
    __syncthreads();
    float acc[NP];
    #pragma unroll
    for (int p = 0; p < NP; ++p) acc[p] = 0.f;
    const float4* sfr = (const float4*)(sf_w + (size_t)c*C_);
    const float4* fL4 = (const float4*)featL;
    for (int c4 = 0; c4 < C_/4; ++c4) {
        float4 wv = sfr[c4];
        #pragma unroll
        for (int p = 0; p < NP; ++p) {
            float4 f = fL4[p*(C_/4) + c4];
            acc[p] += wv.x*f.x + wv.y*f.y + wv.z*f.z + wv.w*f.w;
        }
    }
    #pragma unroll
    for (int p = 0; p < NP; ++p) {
        float v = acc[p];
        acc[p] = v > 0.f ? SELU_SC*v : SELU_SC*SELU_AL*expm1f(v);
    }
    __shared__ __align__(16) float gL[NP*C_];
    #pragma unroll
    for (int p = 0; p < NP; ++p) gL[p*C_ + c] = acc[p];
    __syncthreads();
    float d_acc = 0.f;
    for (int pc = 0; pc < NP*C_; ++pc)
        d_acc += gL[pc] * agg_w[(size_t)pc*C_ + c];
    dst[(size_t)bid*C_ + c] = d_acc;
}

extern "C" void kernel_launch(void* const* d_in, const int* in_sizes, int n_in,
                              void* d_out, int out_size, void* d_ws, size_t ws_size,
                              hipStream_t stream) {
    const float* x    = (const float*)d_in[0];
    const float* kpts = (const float*)d_in[1];
    const float* W1   = (const float*)d_in[2];
    const float* b1   = (const float*)d_in[3];
    const float* W2   = (const float*)d_in[4];
    const float* b2   = (const float*)d_in[5];
    const float* sfw  = (const float*)d_in[6];
    const float* aggw = (const float*)d_in[7];
    float* out_desc = (float*)d_out;
    float* out_off  = out_desc + (size_t)B_*NK*C_;

    char* ws = (char*)d_ws;
    float* pos = (float*)ws;                                  // 512 KB @ 0
    const size_t FEAT_OFF = (size_t)1 << 20;                  // 1 MB, 16 MB
    const size_t SFB_OFF  = (size_t)20 << 20;                 // 32 KB
    const size_t AGG_OFF  = (size_t)21 << 20;                 // 256 KB
    const size_t W1B_OFF  = (size_t)22 << 20;                 // 36 KB
    const size_t XT_OFF   = (size_t)1 << 26;                  // 64 MB, 64 MB
    const size_t XT_BYTES = (size_t)B_*H_*W_*C_*2;
    bool useXT = ws_size >= XT_OFF + XT_BYTES;
    __hip_bfloat16* xtb   = (__hip_bfloat16*)(ws + XT_OFF);
    __hip_bfloat16* featb = (__hip_bfloat16*)(ws + FEAT_OFF);
    __hip_bfloat16* sfb   = (__hip_bfloat16*)(ws + SFB_OFF);
    __hip_bfloat16* aggb  = (__hip_bfloat16*)(ws + AGG_OFF);
    __hip_bfloat16* w1b   = (__hip_bfloat16*)(ws + W1B_OFF);

    if (useXT) {
        k_prep_w1<<<(16*1152 + 255)/256, 256, 0, stream>>>(W1, w1b);
        k_prep_sf<<<128, 256, 0, stream>>>(sfw, sfb);
        k_prep_agg<<<512, 256, 0, stream>>>(aggw, aggb);
        k_transpose_bf<<<B_*H_*(C_/32)*(W_/32), 256, 0, stream>>>(x, xtb);
        k_offsets_mfma<<<NROWS/16, 256, 0, stream>>>(xtb, kpts, w1b, b1, W2, b2, out_off, pos);
        k_gather<<<NROWS, 256, 0, stream>>>(xtb, pos, featb);
        k_tail<<<NROWS/16, 256, 0, stream>>>(featb, sfb, aggb, out_desc);
        k_norm<<<NROWS, 64, 0, stream>>>(out_desc);
    } else {
        k_offsets_f32<<<NROWS, 64, 0, stream>>>(x, kpts, W1, b1, W2, b2, out_off, pos);
        k_sample_f32<<<NROWS, 128, 0, stream>>>(x, pos, sfw, aggw, out_desc);
        k_norm<<<NROWS, 64, 0, stream>>>(out_desc);
    }
}

// Round 6
// 69.538 us; speedup vs baseline: 5.8713x; 1.2421x over previous
//
#include <hip/hip_runtime.h>
#include <hip/hip_bf16.h>
#include <math.h>

#define B_ 4
#define C_ 128
#define H_ 256
#define W_ 256
#define NK 2048
#define NP 8
#define HW_ (H_*W_)
#define MAXOFF 64.0f
#define NROWS (B_*NK)          // 8192

typedef short s16x8 __attribute__((ext_vector_type(8)));
typedef short s16x4 __attribute__((ext_vector_type(4)));
typedef float f32x4 __attribute__((ext_vector_type(4)));

#define SELU_SC 1.0507009873554805f
#define SELU_AL 1.6732632423543772f

#define N_W1F (36*64*8)     // 18432
#define N_SFB (8*4*64*8)    // 16384... (j=8)*(ks=4)*(l=64)*(e=8) = 16384? no: 8*4*64*8 = 16384
// NOTE: sfb actually has 8*4*64*8 = 16384 elems? sf_w is 128x128 = 16384. Correct.
#define N_AGG (8*8*4*64*8)  // 131072

__device__ inline float bf2f(short b) {
    union { unsigned int u; float f; } cv;
    cv.u = ((unsigned int)(unsigned short)b) << 16;
    return cv.f;
}
__device__ inline short f2bf_s(float f) {
    __hip_bfloat16 h = __float2bfloat16(f);
    return *(short*)&h;
}

// ---------------- K0: transpose x (B,C,H,W) fp32 -> xt (B,H,W,C) bf16 -------
__global__ __launch_bounds__(256) void k_transpose_bf(const float* __restrict__ x,
                                                      __hip_bfloat16* __restrict__ xt) {
    __shared__ float tile[32][33];
    int bid = blockIdx.x;
    int xb = bid & 7;  bid >>= 3;
    int cb = bid & 3;  bid >>= 2;
    int y  = bid & 255; bid >>= 8;
    int i  = bid;
    int tx  = threadIdx.x & 31;
    int ty0 = threadIdx.x >> 5;
    const float* src = x + ((size_t)(i*C_ + cb*32)*H_ + y)*W_ + xb*32;
    #pragma unroll
    for (int k = 0; k < 4; ++k) {
        int c = ty0 + k*8;
        tile[c][tx] = src[(size_t)c*HW_ + tx];
    }
    __syncthreads();
    int tx2 = threadIdx.x & 15;
    int xo8 = threadIdx.x >> 4;
    __hip_bfloat16* dst = xt + ((size_t)(i*H_ + y)*W_ + xb*32)*C_ + cb*32;
    #pragma unroll
    for (int k = 0; k < 2; ++k) {
        int xo = xo8 + k*16;
        __hip_bfloat162 v;
        v.x = __float2bfloat16(tile[tx2*2][xo]);
        v.y = __float2bfloat16(tile[tx2*2+1][xo]);
        *(__hip_bfloat162*)(dst + (size_t)xo*C_ + tx2*2) = v;
    }
}

// -------- fused prep: W1 -> w1f frag-linear; sf_w -> sfb; agg_w -> aggb -----
// w1f[ks][l][e]:  W1[o=l&15][c=(ks&3)*32+(l>>4)*8+e][ab=ks>>2]   (ks 0..35)
// sfb[j][ks][l][e]:  sf_w[j*16+(l&15)][ks*32+(l>>4)*8+e]
// aggb[jd][p][ks][l][e]: agg_w[p][ks*32+(l>>4)*8+e][jd*16+(l&15)]
__global__ __launch_bounds__(256) void k_prep_all(const float* __restrict__ W1,
        const float* __restrict__ sf_w, const float* __restrict__ agg_w,
        __hip_bfloat16* __restrict__ w1f, __hip_bfloat16* __restrict__ sfb,
        __hip_bfloat16* __restrict__ aggb) {
    int t = blockIdx.x*256 + threadIdx.x;
    if (t < N_W1F) {
        int e = t & 7, l = (t >> 3) & 63, ks = t >> 9;
        int o = l & 15, c = (ks & 3)*32 + ((l >> 4) << 3) + e, ab = ks >> 2;
        w1f[t] = __float2bfloat16(W1[o*1152 + c*9 + ab]);
    } else if (t < N_W1F + N_SFB) {
        int u = t - N_W1F;
        int e = u & 7, l = (u >> 3) & 63, ks = (u >> 9) & 3, j = u >> 11;
        sfb[u] = __float2bfloat16(sf_w[(j*16 + (l & 15))*128 + ks*32 + ((l >> 4) << 3) + e]);
    } else if (t < N_W1F + N_SFB + N_AGG) {
        int u = t - N_W1F - N_SFB;
        int e = u & 7, l = (u >> 3) & 63, ks = (u >> 9) & 3, p = (u >> 11) & 7, jd = u >> 14;
        aggb[u] = __float2bfloat16(agg_w[((size_t)p*128 + ks*32 + ((l >> 4) << 3) + e)*128 + jd*16 + (l & 15)]);
    }
}

// ------------- K1: fully fused per-16-keypoint pipeline ---------------------
// offsets(MFMA, global frags) -> pos(LDS) -> gather(LDS featL) -> sf+SELU+agg
// (MFMA) -> cross-wave reduce -> L2-norm -> descs. 256 thr / 4 waves.
#define FSTR 1032   // featL row stride (bf16) per keypoint: 2064 B -> 2-way max
#define HSTR 136
#define RSTR 132
__global__ __launch_bounds__(256) void k_fused(
        const __hip_bfloat16* __restrict__ xtb, const float* __restrict__ kpts,
        const __hip_bfloat16* __restrict__ w1f, const float* __restrict__ b1,
        const float* __restrict__ W2, const float* __restrict__ b2,
        const __hip_bfloat16* __restrict__ sfb, const __hip_bfloat16* __restrict__ aggb,
        float* __restrict__ out_off, float* __restrict__ descs) {
    __shared__ __align__(16) char reg0[33792];   // featL (16*1032 bf16) -> red (4*16*132 f32)
    __shared__ __align__(16) char reg1[17408];   // Hl (4 * 16*136 bf16)
    __shared__ float Cp[4][16][17];
    __shared__ float hL[16][17];
    __shared__ float W2s[16][16];
    __shared__ float posL[16][8][2];
    __shared__ float kwx[16], kwy[16];
    __shared__ int   kcx[16], kcy[16];

    int t = threadIdx.x;
    int blk = blockIdx.x;
    int i = blk >> 7;                  // 128 blocks per image
    int w = t >> 6, l = t & 63;
    int r16 = l & 15, q = l >> 4;
    int kp0 = blk * 16;

    if (t < 16) {
        int gk = kp0 + t;
        float kx = kpts[(size_t)gk*2], ky = kpts[(size_t)gk*2 + 1];
        float wx = (kx*0.5f + 0.5f) * (float)(W_-1);
        float wy = (ky*0.5f + 0.5f) * (float)(H_-1);
        int cx = (int)wx - 1; cx = min(max(cx, 0), W_-1-3);
        int cy = (int)wy - 1; cy = min(max(cy, 0), H_-1-3);
        kwx[t] = wx; kwy[t] = wy; kcx[t] = cx; kcy[t] = cy;
    }
    W2s[t >> 4][t & 15] = W2[t];
    __syncthreads();

    // ---- Phase A: patch conv via MFMA, A/B frags straight from global ----
    {
        const char* pb = (const char*)(xtb +
            ((size_t)(i*H_ + kcy[r16])*W_ + kcx[r16])*C_);
        f32x4 acc = {0.f, 0.f, 0.f, 0.f};
        #pragma unroll
        for (int s = 0; s < 9; ++s) {
            int ks = w*9 + s;
            int ab = ks >> 2;
            int a = ab/3, b = ab - (ab/3)*3;
            int off = ((a*W_ + b)*C_ + (ks & 3)*32 + q*8) * 2;
            s16x8 af = *(const s16x8*)(pb + off);
            s16x8 bf = *(const s16x8*)((const short*)w1f + ((size_t)ks*64 + l)*8);
            acc = __builtin_amdgcn_mfma_f32_16x16x32_bf16(af, bf, acc, 0, 0, 0);
        }
        #pragma unroll
        for (int r = 0; r < 4; ++r)
            Cp[w][q*4 + r][r16] = acc[r];
    }
    __syncthreads();
    // ---- MLP + pos ----
    {
        int kp = t >> 4, o = t & 15;
        float sum = Cp[0][kp][o] + Cp[1][kp][o] + Cp[2][kp][o] + Cp[3][kp][o];
        hL[kp][o] = fmaxf(sum + b1[o], 0.f);
        __syncthreads();
        float acc2 = b2[o];
        #pragma unroll
        for (int oo = 0; oo < 16; ++oo)
            acc2 += hL[kp][oo] * W2s[o][oo];
        acc2 = fminf(fmaxf(acc2, -MAXOFF), MAXOFF);
        int d = o >> 3, p = o & 7;
        int gk = kp0 + kp;
        out_off[((size_t)gk*NP + p)*2 + d] = acc2;
        posL[kp][p][d] = (d ? kwy[kp] : kwx[kp]) + acc2;
    }
    __syncthreads();

    // ---- Phase B: bilinear gather -> featL (LDS) ----
    __hip_bfloat16* featL = (__hip_bfloat16*)reg0;
    {
        int half = t >> 5, lane32 = t & 31;
        int c0 = lane32 * 4;
        #pragma unroll 4
        for (int s = 0; s < 16; ++s) {
            int pr = s*8 + half;
            int kp = pr >> 3, p = pr & 7;
            float px = posL[kp][p][0], py = posL[kp][p][1];
            float x0f = floorf(px), y0f = floorf(py);
            int x0 = (int)x0f, y0 = (int)y0f;
            float wx1 = px - x0f, wy1 = py - y0f;
            float wx0 = 1.f - wx1, wy0 = 1.f - wy1;
            float a0 = 0.f, a1 = 0.f, a2 = 0.f, a3 = 0.f;
            #pragma unroll
            for (int tap = 0; tap < 4; ++tap) {
                int xi = x0 + (tap & 1);
                int yi = y0 + (tap >> 1);
                float wgt = ((tap & 1) ? wx1 : wx0) * ((tap >> 1) ? wy1 : wy0);
                bool valid = (xi >= 0) & (xi < W_) & (yi >= 0) & (yi < H_);
                int xc = min(max(xi, 0), W_-1);
                int yc = min(max(yi, 0), H_-1);
                float wv = valid ? wgt : 0.f;
                const __hip_bfloat16* src = xtb + ((size_t)(i*H_ + yc)*W_ + xc)*C_ + c0;
                s16x4 v = *(const s16x4*)src;
                a0 += wv * bf2f(v[0]);
                a1 += wv * bf2f(v[1]);
                a2 += wv * bf2f(v[2]);
                a3 += wv * bf2f(v[3]);
            }
            s16x4 ov;
            ov[0] = f2bf_s(a0); ov[1] = f2bf_s(a1);
            ov[2] = f2bf_s(a2); ov[3] = f2bf_s(a3);
            *(s16x4*)(featL + kp*FSTR + p*C_ + c0) = ov;
        }
    }
    __syncthreads();

    // ---- Phase C: sf GEMM + SELU -> Hl; agg GEMM -> dacc ----
    __hip_bfloat16* Hl = (__hip_bfloat16*)reg1;    // wave w base: + w*16*HSTR
    f32x4 dacc[8];
    #pragma unroll
    for (int jd = 0; jd < 8; ++jd) dacc[jd] = (f32x4){0.f,0.f,0.f,0.f};
    #pragma unroll
    for (int pi = 0; pi < 2; ++pi) {
        int p = w*2 + pi;
        s16x8 af[4];
        #pragma unroll
        for (int ks = 0; ks < 4; ++ks)
            af[ks] = *(const s16x8*)(featL + r16*FSTR + p*C_ + ks*32 + q*8);
        #pragma unroll
        for (int j = 0; j < 8; ++j) {
            f32x4 acc = (f32x4){0.f,0.f,0.f,0.f};
            const short* sb = (const short*)sfb + ((j*4)*64 + l)*8;
            #pragma unroll
            for (int ks = 0; ks < 4; ++ks)
                acc = __builtin_amdgcn_mfma_f32_16x16x32_bf16(af[ks], *(const s16x8*)(sb + ks*512), acc, 0, 0, 0);
            #pragma unroll
            for (int r = 0; r < 4; ++r) {
                float v = acc[r];
                v = v > 0.f ? SELU_SC*v : SELU_SC*SELU_AL*expm1f(v);
                Hl[(size_t)w*16*HSTR + (q*4 + r)*HSTR + j*16 + r16] = __float2bfloat16(v);
            }
        }
        s16x8 ah[4];
        #pragma unroll
        for (int ks = 0; ks < 4; ++ks)
            ah[ks] = *(const s16x8*)(Hl + (size_t)w*16*HSTR + r16*HSTR + ks*32 + q*8);
        #pragma unroll
        for (int jd = 0; jd < 8; ++jd) {
            const short* ab = (const short*)aggb + (((jd*8 + p)*4)*64 + l)*8;
            #pragma unroll
            for (int ks = 0; ks < 4; ++ks)
                dacc[jd] = __builtin_amdgcn_mfma_f32_16x16x32_bf16(ah[ks], *(const s16x8*)(ab + ks*512), dacc[jd], 0, 0, 0);
        }
    }
    __syncthreads();   // all featL reads complete before red overwrites reg0

    float* red = (float*)reg0;   // [4][16][RSTR]
    #pragma unroll
    for (int jd = 0; jd < 8; ++jd)
        #pragma unroll
        for (int r = 0; r < 4; ++r)
            red[((size_t)w*16 + q*4 + r)*RSTR + jd*16 + r16] = dacc[jd][r];
    __syncthreads();

    // ---- fused L2-normalize + store ----
    {
        int row = t >> 4, c0 = t & 15;
        float v[8];
        float ss = 0.f;
        #pragma unroll
        for (int k = 0; k < 8; ++k) {
            int col = c0 + 16*k;
            float s = red[(0*16 + row)*RSTR + col] + red[(1*16 + row)*RSTR + col]
                    + red[(2*16 + row)*RSTR + col] + red[(3*16 + row)*RSTR + col];
            v[k] = s; ss += s*s;
        }
        ss += __shfl_xor(ss, 1);
        ss += __shfl_xor(ss, 2);
        ss += __shfl_xor(ss, 4);
        ss += __shfl_xor(ss, 8);
        float sc = fmaxf(sqrtf(ss), 1e-12f);
        #pragma unroll
        for (int k = 0; k < 8; ++k)
            descs[(size_t)(kp0 + row)*C_ + c0 + 16*k] = v[k] / sc;
    }
}

// ---------------- fallback path (no workspace): fp32 direct -----------------
__global__ __launch_bounds__(64) void k_offsets_f32(const float* __restrict__ xin,
        const float* __restrict__ kpts, const float* __restrict__ W1,
        const float* __restrict__ b1, const float* __restrict__ W2,
        const float* __restrict__ b2, float* __restrict__ out_off,
        float* __restrict__ pos) {
    __shared__ float pL[1152];
    __shared__ float hL2[16];
    __shared__ float oL[16];
    int bid = blockIdx.x;
    int i = bid >> 11;
    int t = threadIdx.x;
    float kx = kpts[(size_t)bid*2 + 0];
    float ky = kpts[(size_t)bid*2 + 1];
    float kwhx = (kx*0.5f + 0.5f) * (float)(W_-1);
    float kwhy = (ky*0.5f + 0.5f) * (float)(H_-1);
    int cx = (int)kwhx - 1; cx = cx < 0 ? 0 : (cx > 252 ? 252 : cx);
    int cy = (int)kwhy - 1; cy = cy < 0 ? 0 : (cy > 252 ? 252 : cy);
    for (int e = t; e < 1152; e += 64) {
        int a = e/384; int r = e - a*384; int b = r >> 7; int c = r & 127;
        pL[e] = xin[(((size_t)(i*C_ + c))*H_ + cy + a)*W_ + cx + b];
    }
    __syncthreads();
    int o = t & 15;
    int chunk = t >> 4;
    float partial = 0.f;
    const float* w1r = W1 + o*1152;
    for (int c = chunk*32; c < chunk*32 + 32; ++c) {
        #pragma unroll
        for (int ab = 0; ab < 9; ++ab) {
            const int a = ab/3, b = ab - (ab/3)*3;
            partial += w1r[c*9 + ab] * pL[a*384 + b*128 + c];
        }
    }
    partial += __shfl_xor(partial, 16);
    partial += __shfl_xor(partial, 32);
    float h1 = fmaxf(partial + b1[o], 0.f);
    if (t < 16) hL2[t] = h1;
    __syncthreads();
    if (t < 16) {
        float acc = b2[t];
        const float* w2r = W2 + t*16;
        #pragma unroll
        for (int oo = 0; oo < 16; ++oo) acc += w2r[oo]*hL2[oo];
        acc = fminf(fmaxf(acc, -MAXOFF), MAXOFF);
        oL[t] = acc;
    }
    __syncthreads();
    if (t < 8) {
        float ox = oL[t], oy = oL[8 + t];
        size_t base = ((size_t)bid*NP + t)*2;
        out_off[base]   = ox;
        out_off[base+1] = oy;
        pos[base]   = kwhx + ox;
        pos[base+1] = kwhy + oy;
    }
}

__global__ __launch_bounds__(128) void k_sample_f32(const float* __restrict__ xin,
        const float* __restrict__ pos, const float* __restrict__ sf_w,
        const float* __restrict__ agg_w, float* __restrict__ dst) {
    __shared__ __align__(16) float featL[NP*C_];
    __shared__ float pp[16];
    int bid = blockIdx.x;
    int i = bid >> 11;
    int c = threadIdx.x;
    if (c < 16) pp[c] = pos[(size_t)bid*16 + c];
    __syncthreads();
    #pragma unroll
    for (int p = 0; p < NP; ++p) {
        float px = pp[p*2], py = pp[p*2+1];
        float x0f = floorf(px), y0f = floorf(py);
        int x0 = (int)x0f, y0 = (int)y0f;
        float wx1 = px - x0f, wy1 = py - y0f;
        float wx0 = 1.f - wx1, wy0 = 1.f - wy1;
        float acc = 0.f;
        #pragma unroll
        for (int tap = 0; tap < 4; ++tap) {
            int xi = x0 + (tap & 1);
            int yi = y0 + (tap >> 1);
            float w = ((tap & 1) ? wx1 : wx0) * ((tap >> 1) ? wy1 : wy0);
            bool valid = (xi >= 0) & (xi < W_) & (yi >= 0) & (yi < H_);
            int xc = min(max(xi, 0), W_-1);
            int yc = min(max(yi, 0), H_-1);
            acc += (valid ? w : 0.f) * xin[(((size_t)(i*C_ + c))*H_ + yc)*W_ + xc];
        }
        featL[p*C_ + c] = acc;
    }
    __syncthreads();
    float acc[NP];
    #pragma unroll
    for (int p = 0; p < NP; ++p) acc[p] = 0.f;
    const float4* sfr = (const float4*)(sf_w + (size_t)c*C_);
    const float4* fL4 = (const float4*)featL;
    for (int c4 = 0; c4 < C_/4; ++c4) {
        float4 wv = sfr[c4];
        #pragma unroll
        for (int p = 0; p < NP; ++p) {
            float4 f = fL4[p*(C_/4) + c4];
            acc[p] += wv.x*f.x + wv.y*f.y + wv.z*f.z + wv.w*f.w;
        }
    }
    #pragma unroll
    for (int p = 0; p < NP; ++p) {
        float v = acc[p];
        acc[p] = v > 0.f ? SELU_SC*v : SELU_SC*SELU_AL*expm1f(v);
    }
    __shared__ __align__(16) float gL[NP*C_];
    #pragma unroll
    for (int p = 0; p < NP; ++p) gL[p*C_ + c] = acc[p];
    __syncthreads();
    float d_acc = 0.f;
    for (int pc = 0; pc < NP*C_; ++pc)
        d_acc += gL[pc] * agg_w[(size_t)pc*C_ + c];
    dst[(size_t)bid*C_ + c] = d_acc;
}

__global__ __launch_bounds__(64) void k_norm(float* __restrict__ out) {
    int row = blockIdx.x;
    int l = threadIdx.x;
    float* r = out + (size_t)row*C_;
    float a = r[l], b = r[l+64];
    float ss = a*a + b*b;
    #pragma unroll
    for (int m = 1; m < 64; m <<= 1) ss += __shfl_xor(ss, m);
    float s = fmaxf(sqrtf(ss), 1e-12f);
    r[l] = a/s; r[l+64] = b/s;
}

extern "C" void kernel_launch(void* const* d_in, const int* in_sizes, int n_in,
                              void* d_out, int out_size, void* d_ws, size_t ws_size,
                              hipStream_t stream) {
    const float* x    = (const float*)d_in[0];
    const float* kpts = (const float*)d_in[1];
    const float* W1   = (const float*)d_in[2];
    const float* b1   = (const float*)d_in[3];
    const float* W2   = (const float*)d_in[4];
    const float* b2   = (const float*)d_in[5];
    const float* sfw  = (const float*)d_in[6];
    const float* aggw = (const float*)d_in[7];
    float* out_desc = (float*)d_out;
    float* out_off  = out_desc + (size_t)B_*NK*C_;

    char* ws = (char*)d_ws;
    float* pos = (float*)ws;                                  // fallback only
    const size_t W1F_OFF = (size_t)1 << 20;
    const size_t SFB_OFF = (size_t)2 << 20;
    const size_t AGG_OFF = (size_t)3 << 20;
    const size_t XT_OFF  = (size_t)1 << 26;                   // 64 MB
    const size_t XT_BYTES = (size_t)B_*H_*W_*C_*2;            // 64 MB
    bool useXT = ws_size >= XT_OFF + XT_BYTES;
    __hip_bfloat16* xtb  = (__hip_bfloat16*)(ws + XT_OFF);
    __hip_bfloat16* w1f  = (__hip_bfloat16*)(ws + W1F_OFF);
    __hip_bfloat16* sfb  = (__hip_bfloat16*)(ws + SFB_OFF);
    __hip_bfloat16* aggb = (__hip_bfloat16*)(ws + AGG_OFF);

    if (useXT) {
        const int NPREP = N_W1F + N_SFB + N_AGG;
        k_prep_all<<<(NPREP + 255)/256, 256, 0, stream>>>(W1, sfw, aggw, w1f, sfb, aggb);
        k_transpose_bf<<<B_*H_*(C_/32)*(W_/32), 256, 0, stream>>>(x, xtb);
        k_fused<<<NROWS/16, 256, 0, stream>>>(xtb, kpts, w1f, b1, W2, b2, sfb, aggb,
                                              out_off, out_desc);
    } else {
        k_offsets_f32<<<NROWS, 64, 0, stream>>>(x, kpts, W1, b1, W2, b2, out_off, pos);
        k_sample_f32<<<NROWS, 128, 0, stream>>>(x, pos, sfw, aggw, out_desc);
        k_norm<<<NROWS, 64, 0, stream>>>(out_desc);
    }
}

// Round 7
// 66.828 us; speedup vs baseline: 6.1093x; 1.0405x over previous
//
#include <hip/hip_runtime.h>
#include <hip/hip_bf16.h>
#include <math.h>

#define B_ 4
#define C_ 128
#define H_ 256
#define W_ 256
#define NK 2048
#define NP 8
#define HW_ (H_*W_)
#define MAXOFF 64.0f
#define NROWS (B_*NK)          // 8192

typedef short s16x8 __attribute__((ext_vector_type(8)));
typedef short s16x4 __attribute__((ext_vector_type(4)));
typedef float f32x4 __attribute__((ext_vector_type(4)));

#define SELU_SC 1.0507009873554805f
#define SELU_AL 1.6732632423543772f

#define N_W1F (36*64*8)     // 18432
#define N_SFB (8*4*64*8)    // 16384
#define N_AGG (8*8*4*64*8)  // 131072
#define NPREP (N_W1F + N_SFB + N_AGG)   // 165888
#define NT_BLK (B_*H_*(C_/32)*(W_/32))  // 8192 transpose blocks
#define NP_BLK 81                        // 81*256*8 = 165888 prep elems

__device__ inline float bf2f(short b) {
    union { unsigned int u; float f; } cv;
    cv.u = ((unsigned int)(unsigned short)b) << 16;
    return cv.f;
}
__device__ inline short f2bf_s(float f) {
    __hip_bfloat16 h = __float2bfloat16(f);
    return *(short*)&h;
}

// ---- K0: transpose x (B,C,H,W) fp32 -> xt (B,H,W,C) bf16  (+ fused preps) --
// blocks [0, NT_BLK): transpose; blocks [NT_BLK, NT_BLK+NP_BLK): weight prep.
__global__ __launch_bounds__(256) void k_transpose_prep(const float* __restrict__ x,
        __hip_bfloat16* __restrict__ xt,
        const float* __restrict__ W1, const float* __restrict__ sf_w,
        const float* __restrict__ agg_w,
        __hip_bfloat16* __restrict__ w1f, __hip_bfloat16* __restrict__ sfb,
        __hip_bfloat16* __restrict__ aggb) {
    __shared__ float tile[32][33];
    int bid = blockIdx.x;
    if (bid >= NT_BLK) {
        // ---- weight prep: 8 elems per thread ----
        int base = ((bid - NT_BLK)*256 + threadIdx.x)*8;
        #pragma unroll
        for (int j = 0; j < 8; ++j) {
            int t = base + j;
            if (t < N_W1F) {
                int e = t & 7, l = (t >> 3) & 63, ks = t >> 9;
                int o = l & 15, c = (ks & 3)*32 + ((l >> 4) << 3) + e, ab = ks >> 2;
                w1f[t] = __float2bfloat16(W1[o*1152 + c*9 + ab]);
            } else if (t < N_W1F + N_SFB) {
                int u = t - N_W1F;
                int e = u & 7, l = (u >> 3) & 63, ks = (u >> 9) & 3, jj = u >> 11;
                sfb[u] = __float2bfloat16(sf_w[(jj*16 + (l & 15))*128 + ks*32 + ((l >> 4) << 3) + e]);
            } else if (t < NPREP) {
                int u = t - N_W1F - N_SFB;
                int e = u & 7, l = (u >> 3) & 63, ks = (u >> 9) & 3, p = (u >> 11) & 7, jd = u >> 14;
                aggb[u] = __float2bfloat16(agg_w[((size_t)p*128 + ks*32 + ((l >> 4) << 3) + e)*128 + jd*16 + (l & 15)]);
            }
        }
        return;
    }
    int xb = bid & 7;  bid >>= 3;
    int cb = bid & 3;  bid >>= 2;
    int y  = bid & 255; bid >>= 8;
    int i  = bid;
    int tx  = threadIdx.x & 31;
    int ty0 = threadIdx.x >> 5;
    const float* src = x + ((size_t)(i*C_ + cb*32)*H_ + y)*W_ + xb*32;
    #pragma unroll
    for (int k = 0; k < 4; ++k) {
        int c = ty0 + k*8;
        tile[c][tx] = src[(size_t)c*HW_ + tx];
    }
    __syncthreads();
    int tx2 = threadIdx.x & 15;
    int xo8 = threadIdx.x >> 4;
    __hip_bfloat16* dst = xt + ((size_t)(i*H_ + y)*W_ + xb*32)*C_ + cb*32;
    #pragma unroll
    for (int k = 0; k < 2; ++k) {
        int xo = xo8 + k*16;
        __hip_bfloat162 v;
        v.x = __float2bfloat16(tile[tx2*2][xo]);
        v.y = __float2bfloat16(tile[tx2*2+1][xo]);
        *(__hip_bfloat162*)(dst + (size_t)xo*C_ + tx2*2) = v;
    }
}

// ------------- K1: fully fused per-16-keypoint pipeline ---------------------
// LDS overlay: smem serves Cp/hL (phase A) -> featL (B) -> Hl+red (C).
// 36 KB total -> 4 blocks/CU; launch_bounds(256,4) pins VGPR<=128.
#define FSTR 1032   // featL row stride (bf16): uniform-bank b128 reads
#define HSTR 136
#define RSTR 132
__global__ __launch_bounds__(256, 4) void k_fused(
        const __hip_bfloat16* __restrict__ xtb, const float* __restrict__ kpts,
        const __hip_bfloat16* __restrict__ w1f, const float* __restrict__ b1,
        const float* __restrict__ W2, const float* __restrict__ b2,
        const __hip_bfloat16* __restrict__ sfb, const __hip_bfloat16* __restrict__ aggb,
        float* __restrict__ out_off, float* __restrict__ descs) {
    __shared__ __align__(16) char smem[33792];
    __shared__ float W2s[16][16];
    __shared__ float posL[16][8][2];
    __shared__ float kwx[16], kwy[16];
    __shared__ int   kcx[16], kcy[16];

    int t = threadIdx.x;
    int blk = blockIdx.x;
    int i = blk >> 7;                  // 128 blocks per image
    int w = t >> 6, l = t & 63;
    int r16 = l & 15, q = l >> 4;
    int kp0 = blk * 16;

    if (t < 16) {
        int gk = kp0 + t;
        float kx = kpts[(size_t)gk*2], ky = kpts[(size_t)gk*2 + 1];
        float wx = (kx*0.5f + 0.5f) * (float)(W_-1);
        float wy = (ky*0.5f + 0.5f) * (float)(H_-1);
        int cx = (int)wx - 1; cx = min(max(cx, 0), W_-1-3);
        int cy = (int)wy - 1; cy = min(max(cy, 0), H_-1-3);
        kwx[t] = wx; kwy[t] = wy; kcx[t] = cx; kcy[t] = cy;
    }
    W2s[t >> 4][t & 15] = W2[t];
    __syncthreads();

    // ---- Phase A: patch conv via MFMA, A/B frags straight from global ----
    float* Cp  = (float*)smem;           // [4][16][17]
    float* hLr = (float*)(smem + 4352);  // [16][17]
    {
        const char* pb = (const char*)(xtb +
            ((size_t)(i*H_ + kcy[r16])*W_ + kcx[r16])*C_);
        f32x4 acc = {0.f, 0.f, 0.f, 0.f};
        #pragma unroll
        for (int s = 0; s < 9; ++s) {
            int ks = w*9 + s;
            int ab = ks >> 2;
            int a = ab/3, b = ab - (ab/3)*3;
            int off = ((a*W_ + b)*C_ + (ks & 3)*32 + q*8) * 2;
            s16x8 af = *(const s16x8*)(pb + off);
            s16x8 bf = *(const s16x8*)((const short*)w1f + ((size_t)ks*64 + l)*8);
            acc = __builtin_amdgcn_mfma_f32_16x16x32_bf16(af, bf, acc, 0, 0, 0);
        }
        #pragma unroll
        for (int r = 0; r < 4; ++r)
            Cp[(w*16 + q*4 + r)*17 + r16] = acc[r];
    }
    __syncthreads();
    // ---- MLP + pos ----
    {
        int kp = t >> 4, o = t & 15;
        float sum = Cp[(0*16 + kp)*17 + o] + Cp[(1*16 + kp)*17 + o]
                  + Cp[(2*16 + kp)*17 + o] + Cp[(3*16 + kp)*17 + o];
        hLr[kp*17 + o] = fmaxf(sum + b1[o], 0.f);
        __syncthreads();
        float acc2 = b2[o];
        #pragma unroll
        for (int oo = 0; oo < 16; ++oo)
            acc2 += hLr[kp*17 + oo] * W2s[o][oo];
        acc2 = fminf(fmaxf(acc2, -MAXOFF), MAXOFF);
        int d = o >> 3, p = o & 7;
        int gk = kp0 + kp;
        out_off[((size_t)gk*NP + p)*2 + d] = acc2;
        posL[kp][p][d] = (d ? kwy[kp] : kwx[kp]) + acc2;
    }
    __syncthreads();   // Cp/hL dead; smem becomes featL

    // ---- Phase B: bilinear gather -> featL (LDS) ----
    __hip_bfloat16* featL = (__hip_bfloat16*)smem;
    {
        int half = t >> 5, lane32 = t & 31;
        int c0 = lane32 * 4;
        #pragma unroll 4
        for (int s = 0; s < 16; ++s) {
            int pr = s*8 + half;
            int kp = pr >> 3, p = pr & 7;
            float px = posL[kp][p][0], py = posL[kp][p][1];
            float x0f = floorf(px), y0f = floorf(py);
            int x0 = (int)x0f, y0 = (int)y0f;
            float wx1 = px - x0f, wy1 = py - y0f;
            float wx0 = 1.f - wx1, wy0 = 1.f - wy1;
            float a0 = 0.f, a1 = 0.f, a2 = 0.f, a3 = 0.f;
            #pragma unroll
            for (int tap = 0; tap < 4; ++tap) {
                int xi = x0 + (tap & 1);
                int yi = y0 + (tap >> 1);
                float wgt = ((tap & 1) ? wx1 : wx0) * ((tap >> 1) ? wy1 : wy0);
                bool valid = (xi >= 0) & (xi < W_) & (yi >= 0) & (yi < H_);
                int xc = min(max(xi, 0), W_-1);
                int yc = min(max(yi, 0), H_-1);
                float wv = valid ? wgt : 0.f;
                const __hip_bfloat16* src = xtb + ((size_t)(i*H_ + yc)*W_ + xc)*C_ + c0;
                s16x4 v = *(const s16x4*)src;
                a0 += wv * bf2f(v[0]);
                a1 += wv * bf2f(v[1]);
                a2 += wv * bf2f(v[2]);
                a3 += wv * bf2f(v[3]);
            }
            s16x4 ov;
            ov[0] = f2bf_s(a0); ov[1] = f2bf_s(a1);
            ov[2] = f2bf_s(a2); ov[3] = f2bf_s(a3);
            *(s16x4*)(featL + kp*FSTR + p*C_ + c0) = ov;
        }
    }
    __syncthreads();

    // ---- Phase C: preload ALL A-frags, then featL region is reused ----
    s16x8 af[2][4];
    #pragma unroll
    for (int pi = 0; pi < 2; ++pi) {
        int p = w*2 + pi;
        #pragma unroll
        for (int ks = 0; ks < 4; ++ks)
            af[pi][ks] = *(const s16x8*)(featL + r16*FSTR + p*C_ + ks*32 + q*8);
    }
    __syncthreads();   // all featL reads done; smem becomes Hl (per-wave) / red

    __hip_bfloat16* Hl = (__hip_bfloat16*)(smem + (size_t)w*8448);  // [16][HSTR]
    f32x4 dacc[8];
    #pragma unroll
    for (int jd = 0; jd < 8; ++jd) dacc[jd] = (f32x4){0.f,0.f,0.f,0.f};
    #pragma unroll
    for (int pi = 0; pi < 2; ++pi) {
        int p = w*2 + pi;
        #pragma unroll
        for (int j = 0; j < 8; ++j) {
            f32x4 acc = (f32x4){0.f,0.f,0.f,0.f};
            const short* sb = (const short*)sfb + ((j*4)*64 + l)*8;
            #pragma unroll
            for (int ks = 0; ks < 4; ++ks)
                acc = __builtin_amdgcn_mfma_f32_16x16x32_bf16(af[pi][ks], *(const s16x8*)(sb + ks*512), acc, 0, 0, 0);
            #pragma unroll
            for (int r = 0; r < 4; ++r) {
                float v = acc[r];
                v = v > 0.f ? SELU_SC*v : SELU_SC*SELU_AL*expm1f(v);
                Hl[(q*4 + r)*HSTR + j*16 + r16] = __float2bfloat16(v);
            }
        }
        s16x8 ah[4];
        #pragma unroll
        for (int ks = 0; ks < 4; ++ks)
            ah[ks] = *(const s16x8*)(Hl + r16*HSTR + ks*32 + q*8);
        #pragma unroll
        for (int jd = 0; jd < 8; ++jd) {
            const short* ab = (const short*)aggb + (((jd*8 + p)*4)*64 + l)*8;
            #pragma unroll
            for (int ks = 0; ks < 4; ++ks)
                dacc[jd] = __builtin_amdgcn_mfma_f32_16x16x32_bf16(ah[ks], *(const s16x8*)(ab + ks*512), dacc[jd], 0, 0, 0);
        }
    }
    __syncthreads();   // all Hl reads done; smem becomes red [4][16][RSTR]

    float* red = (float*)smem;
    #pragma unroll
    for (int jd = 0; jd < 8; ++jd)
        #pragma unroll
        for (int r = 0; r < 4; ++r)
            red[((size_t)w*16 + q*4 + r)*RSTR + jd*16 + r16] = dacc[jd][r];
    __syncthreads();

    // ---- fused L2-normalize + store ----
    {
        int row = t >> 4, c0 = t & 15;
        float v[8];
        float ss = 0.f;
        #pragma unroll
        for (int k = 0; k < 8; ++k) {
            int col = c0 + 16*k;
            float s = red[(0*16 + row)*RSTR + col] + red[(1*16 + row)*RSTR + col]
                    + red[(2*16 + row)*RSTR + col] + red[(3*16 + row)*RSTR + col];
            v[k] = s; ss += s*s;
        }
        ss += __shfl_xor(ss, 1);
        ss += __shfl_xor(ss, 2);
        ss += __shfl_xor(ss, 4);
        ss += __shfl_xor(ss, 8);
        float sc = fmaxf(sqrtf(ss), 1e-12f);
        #pragma unroll
        for (int k = 0; k < 8; ++k)
            descs[(size_t)(kp0 + row)*C_ + c0 + 16*k] = v[k] / sc;
    }
}

// ---------------- fallback path (no workspace): fp32 direct -----------------
__global__ __launch_bounds__(64) void k_offsets_f32(const float* __restrict__ xin,
        const float* __restrict__ kpts, const float* __restrict__ W1,
        const float* __restrict__ b1, const float* __restrict__ W2,
        const float* __restrict__ b2, float* __restrict__ out_off,
        float* __restrict__ pos) {
    __shared__ float pL[1152];
    __shared__ float hL2[16];
    __shared__ float oL[16];
    int bid = blockIdx.x;
    int i = bid >> 11;
    int t = threadIdx.x;
    float kx = kpts[(size_t)bid*2 + 0];
    float ky = kpts[(size_t)bid*2 + 1];
    float kwhx = (kx*0.5f + 0.5f) * (float)(W_-1);
    float kwhy = (ky*0.5f + 0.5f) * (float)(H_-1);
    int cx = (int)kwhx - 1; cx = cx < 0 ? 0 : (cx > 252 ? 252 : cx);
    int cy = (int)kwhy - 1; cy = cy < 0 ? 0 : (cy > 252 ? 252 : cy);
    for (int e = t; e < 1152; e += 64) {
        int a = e/384; int r = e - a*384; int b = r >> 7; int c = r & 127;
        pL[e] = xin[(((size_t)(i*C_ + c))*H_ + cy + a)*W_ + cx + b];
    }
    __syncthreads();
    int o = t & 15;
    int chunk = t >> 4;
    float partial = 0.f;
    const float* w1r = W1 + o*1152;
    for (int c = chunk*32; c < chunk*32 + 32; ++c) {
        #pragma unroll
        for (int ab = 0; ab < 9; ++ab) {
            const int a = ab/3, b = ab - (ab/3)*3;
            partial += w1r[c*9 + ab] * pL[a*384 + b*128 + c];
        }
    }
    partial += __shfl_xor(partial, 16);
    partial += __shfl_xor(partial, 32);
    float h1 = fmaxf(partial + b1[o], 0.f);
    if (t < 16) hL2[t] = h1;
    __syncthreads();
    if (t < 16) {
        float acc = b2[t];
        const float* w2r = W2 + t*16;
        #pragma unroll
        for (int oo = 0; oo < 16; ++oo) acc += w2r[oo]*hL2[oo];
        acc = fminf(fmaxf(acc, -MAXOFF), MAXOFF);
        oL[t] = acc;
    }
    __syncthreads();
    if (t < 8) {
        float ox = oL[t], oy = oL[8 + t];
        size_t base = ((size_t)bid*NP + t)*2;
        out_off[base]   = ox;
        out_off[base+1] = oy;
        pos[base]   = kwhx + ox;
        pos[base+1] = kwhy + oy;
    }
}

__global__ __launch_bounds__(128) void k_sample_f32(const float* __restrict__ xin,
        const float* __restrict__ pos, const float* __restrict__ sf_w,
        const float* __restrict__ agg_w, float* __restrict__ dst) {
    __shared__ __align__(16) float featL[NP*C_];
    __shared__ float pp[16];
    int bid = blockIdx.x;
    int i = bid >> 11;
    int c = threadIdx.x;
    if (c < 16) pp[c] = pos[(size_t)bid*16 + c];
    __syncthreads();
    #pragma unroll
    for (int p = 0; p < NP; ++p) {
        float px = pp[p*2], py = pp[p*2+1];
        float x0f = floorf(px), y0f = floorf(py);
        int x0 = (int)x0f, y0 = (int)y0f;
        float wx1 = px - x0f, wy1 = py - y0f;
        float wx0 = 1.f - wx1, wy0 = 1.f - wy1;
        float acc = 0.f;
        #pragma unroll
        for (int tap = 0; tap < 4; ++tap) {
            int xi = x0 + (tap & 1);
            int yi = y0 + (tap >> 1);
            float w = ((tap & 1) ? wx1 : wx0) * ((tap >> 1) ? wy1 : wy0);
            bool valid = (xi >= 0) & (xi < W_) & (yi >= 0) & (yi < H_);
            int xc = min(max(xi, 0), W_-1);
            int yc = min(max(yi, 0), H_-1);
            acc += (valid ? w : 0.f) * xin[(((size_t)(i*C_ + c))*H_ + yc)*W_ + xc];
        }
        featL[p*C_ + c] = acc;
    }
    __syncthreads();
    float acc[NP];
    #pragma unroll
    for (int p = 0; p < NP; ++p) acc[p] = 0.f;
    const float4* sfr = (const float4*)(sf_w + (size_t)c*C_);
    const float4* fL4 = (const float4*)featL;
    for (int c4 = 0; c4 < C_/4; ++c4) {
        float4 wv = sfr[c4];
        #pragma unroll
        for (int p = 0; p < NP; ++p) {
            float4 f = fL4[p*(C_/4) + c4];
            acc[p] += wv.x*f.x + wv.y*f.y + wv.z*f.z + wv.w*f.w;
        }
    }
    #pragma unroll
    for (int p = 0; p < NP; ++p) {
        float v = acc[p];
        acc[p] = v > 0.f ? SELU_SC*v : SELU_SC*SELU_AL*expm1f(v);
    }
    __shared__ __align__(16) float gL[NP*C_];
    #pragma unroll
    for (int p = 0; p < NP; ++p) gL[p*C_ + c] = acc[p];
    __syncthreads();
    float d_acc = 0.f;
    for (int pc = 0; pc < NP*C_; ++pc)
        d_acc += gL[pc] * agg_w[(size_t)pc*C_ + c];
    dst[(size_t)bid*C_ + c] = d_acc;
}

__global__ __launch_bounds__(64) void k_norm(float* __restrict__ out) {
    int row = blockIdx.x;
    int l = threadIdx.x;
    float* r = out + (size_t)row*C_;
    float a = r[l], b = r[l+64];
    float ss = a*a + b*b;
    #pragma unroll
    for (int m = 1; m < 64; m <<= 1) ss += __shfl_xor(ss, m);
    float s = fmaxf(sqrtf(ss), 1e-12f);
    r[l] = a/s; r[l+64] = b/s;
}

extern "C" void kernel_launch(void* const* d_in, const int* in_sizes, int n_in,
                              void* d_out, int out_size, void* d_ws, size_t ws_size,
                              hipStream_t stream) {
    const float* x    = (const float*)d_in[0];
    const float* kpts = (const float*)d_in[1];
    const float* W1   = (const float*)d_in[2];
    const float* b1   = (const float*)d_in[3];
    const float* W2   = (const float*)d_in[4];
    const float* b2   = (const float*)d_in[5];
    const float* sfw  = (const float*)d_in[6];
    const float* aggw = (const float*)d_in[7];
    float* out_desc = (float*)d_out;
    float* out_off  = out_desc + (size_t)B_*NK*C_;

    char* ws = (char*)d_ws;
    float* pos = (float*)ws;                                  // fallback only
    const size_t W1F_OFF = (size_t)1 << 20;
    const size_t SFB_OFF = (size_t)2 << 20;
    const size_t AGG_OFF = (size_t)3 << 20;
    const size_t XT_OFF  = (size_t)1 << 26;                   // 64 MB
    const size_t XT_BYTES = (size_t)B_*H_*W_*C_*2;            // 64 MB
    bool useXT = ws_size >= XT_OFF + XT_BYTES;
    __hip_bfloat16* xtb  = (__hip_bfloat16*)(ws + XT_OFF);
    __hip_bfloat16* w1f  = (__hip_bfloat16*)(ws + W1F_OFF);
    __hip_bfloat16* sfb  = (__hip_bfloat16*)(ws + SFB_OFF);
    __hip_bfloat16* aggb = (__hip_bfloat16*)(ws + AGG_OFF);

    if (useXT) {
        k_transpose_prep<<<NT_BLK + NP_BLK, 256, 0, stream>>>(x, xtb, W1, sfw, aggw,
                                                              w1f, sfb, aggb);
        k_fused<<<NROWS/16, 256, 0, stream>>>(xtb, kpts, w1f, b1, W2, b2, sfb, aggb,
                                              out_off, out_desc);
    } else {
        k_offsets_f32<<<NROWS, 64, 0, stream>>>(x, kpts, W1, b1, W2, b2, out_off, pos);
        k_sample_f32<<<NROWS, 128, 0, stream>>>(x, pos, sfw, aggw, out_desc);
        k_norm<<<NROWS, 64, 0, stream>>>(out_desc);
    }
}

// Round 8
// 65.091 us; speedup vs baseline: 6.2724x; 1.0267x over previous
//
#include <hip/hip_runtime.h>
#include <hip/hip_bf16.h>
#include <math.h>

#define B_ 4
#define C_ 128
#define H_ 256
#define W_ 256
#define NK 2048
#define NP 8
#define HW_ (H_*W_)
#define MAXOFF 64.0f
#define NROWS (B_*NK)          // 8192

typedef short s16x8 __attribute__((ext_vector_type(8)));
typedef short s16x4 __attribute__((ext_vector_type(4)));
typedef float f32x4 __attribute__((ext_vector_type(4)));

#define SELU_SC 1.0507009873554805f
#define SELU_AL 1.6732632423543772f

#define N_W1F (36*64*8)     // 18432
#define N_SFB (8*4*64*8)    // 16384
#define N_AGG (8*8*4*64*8)  // 131072
#define NPREP (N_W1F + N_SFB + N_AGG)   // 165888
#define NT_BLK (B_*HW_/64)               // 4096 transpose tiles (64 px x 128 ch)
#define NP_BLK 81                        // 81*256*8 = 165888 prep elems
#define LSTR 136                         // LDS row stride (bf16), 272 B

__device__ inline float bf2f(short b) {
    union { unsigned int u; float f; } cv;
    cv.u = ((unsigned int)(unsigned short)b) << 16;
    return cv.f;
}
__device__ inline short f2bf_s(float f) {
    __hip_bfloat16 h = __float2bfloat16(f);
    return *(short*)&h;
}

// ---- K0: transpose x (B,C,H,W) fp32 -> xt (B,H,W,C) bf16  (+ fused preps) --
// Tile = 64 consecutive hw pixels x 128 channels. Reads: 4x256B contiguous
// fp32 segs per wave. Writes: 1KB fully contiguous per wave (no partial-line
// RMW). blocks [NT_BLK, NT_BLK+NP_BLK): weight prep.
__global__ __launch_bounds__(256) void k_transpose_prep(const float* __restrict__ x,
        __hip_bfloat16* __restrict__ xt,
        const float* __restrict__ W1, const float* __restrict__ sf_w,
        const float* __restrict__ agg_w,
        __hip_bfloat16* __restrict__ w1f, __hip_bfloat16* __restrict__ sfb,
        __hip_bfloat16* __restrict__ aggb) {
    __shared__ __align__(16) __hip_bfloat16 lt[64*LSTR];
    int bid = blockIdx.x;
    int t = threadIdx.x;
    if (bid >= NT_BLK) {
        // ---- weight prep: 8 elems per thread ----
        int base = ((bid - NT_BLK)*256 + t)*8;
        #pragma unroll
        for (int j = 0; j < 8; ++j) {
            int u0 = base + j;
            if (u0 < N_W1F) {
                int e = u0 & 7, l = (u0 >> 3) & 63, ks = u0 >> 9;
                int o = l & 15, c = (ks & 3)*32 + ((l >> 4) << 3) + e, ab = ks >> 2;
                w1f[u0] = __float2bfloat16(W1[o*1152 + c*9 + ab]);
            } else if (u0 < N_W1F + N_SFB) {
                int u = u0 - N_W1F;
                int e = u & 7, l = (u >> 3) & 63, ks = (u >> 9) & 3, jj = u >> 11;
                sfb[u] = __float2bfloat16(sf_w[(jj*16 + (l & 15))*128 + ks*32 + ((l >> 4) << 3) + e]);
            } else if (u0 < NPREP) {
                int u = u0 - N_W1F - N_SFB;
                int e = u & 7, l = (u >> 3) & 63, ks = (u >> 9) & 3, p = (u >> 11) & 7, jd = u >> 14;
                aggb[u] = __float2bfloat16(agg_w[((size_t)p*128 + ks*32 + ((l >> 4) << 3) + e)*128 + jd*16 + (l & 15)]);
            }
        }
        return;
    }
    int i = bid >> 10;                 // 1024 tiles per image
    int hw0 = (bid & 1023) * 64;
    const float* src = x + (size_t)i*C_*HW_ + hw0;
    #pragma unroll
    for (int k = 0; k < 8; ++k) {
        int f = t + k*256;             // 0..2047 float4-chunks
        int c = f >> 4, hq = f & 15;
        float4 v = *(const float4*)(src + (size_t)c*HW_ + hq*4);
        int hw = hq*4;
        lt[(hw+0)*LSTR + c] = __float2bfloat16(v.x);
        lt[(hw+1)*LSTR + c] = __float2bfloat16(v.y);
        lt[(hw+2)*LSTR + c] = __float2bfloat16(v.z);
        lt[(hw+3)*LSTR + c] = __float2bfloat16(v.w);
    }
    __syncthreads();
    __hip_bfloat16* dst = xt + ((size_t)i*HW_ + hw0)*C_;
    #pragma unroll
    for (int k = 0; k < 4; ++k) {
        int e = t + k*256;             // 0..1023 16B-chunks
        int hw = e >> 4, c0 = (e & 15)*8;
        *(s16x8*)(dst + (size_t)hw*C_ + c0) = *(const s16x8*)&lt[hw*LSTR + c0];
    }
}

// ------------- K1: fully fused per-16-keypoint pipeline ---------------------
// LDS overlay: smem serves Cp/hL (phase A) -> featL (B) -> Hl+red (C).
#define FSTR 1032   // featL row stride (bf16)
#define HSTR 136
#define RSTR 132
__global__ __launch_bounds__(256, 4) void k_fused(
        const __hip_bfloat16* __restrict__ xtb, const float* __restrict__ kpts,
        const __hip_bfloat16* __restrict__ w1f, const float* __restrict__ b1,
        const float* __restrict__ W2, const float* __restrict__ b2,
        const __hip_bfloat16* __restrict__ sfb, const __hip_bfloat16* __restrict__ aggb,
        float* __restrict__ out_off, float* __restrict__ descs) {
    __shared__ __align__(16) char smem[33792];
    __shared__ float W2s[16][16];
    __shared__ float posL[16][8][2];
    __shared__ float kwx[16], kwy[16];
    __shared__ int   kcx[16], kcy[16];

    int t = threadIdx.x;
    int blk = blockIdx.x;
    int i = blk >> 7;                  // 128 blocks per image
    int w = t >> 6, l = t & 63;
    int r16 = l & 15, q = l >> 4;
    int kp0 = blk * 16;

    if (t < 16) {
        int gk = kp0 + t;
        float kx = kpts[(size_t)gk*2], ky = kpts[(size_t)gk*2 + 1];
        float wx = (kx*0.5f + 0.5f) * (float)(W_-1);
        float wy = (ky*0.5f + 0.5f) * (float)(H_-1);
        int cx = (int)wx - 1; cx = min(max(cx, 0), W_-1-3);
        int cy = (int)wy - 1; cy = min(max(cy, 0), H_-1-3);
        kwx[t] = wx; kwy[t] = wy; kcx[t] = cx; kcy[t] = cy;
    }
    W2s[t >> 4][t & 15] = W2[t];
    __syncthreads();

    // ---- Phase A: patch conv via MFMA, A/B frags straight from global ----
    float* Cp  = (float*)smem;           // [4][16][17]
    float* hLr = (float*)(smem + 4352);  // [16][17]
    {
        const char* pb = (const char*)(xtb +
            ((size_t)(i*H_ + kcy[r16])*W_ + kcx[r16])*C_);
        f32x4 acc = {0.f, 0.f, 0.f, 0.f};
        #pragma unroll
        for (int s = 0; s < 9; ++s) {
            int ks = w*9 + s;
            int ab = ks >> 2;
            int a = ab/3, b = ab - (ab/3)*3;
            int off = ((a*W_ + b)*C_ + (ks & 3)*32 + q*8) * 2;
            s16x8 af = *(const s16x8*)(pb + off);
            s16x8 bf = *(const s16x8*)((const short*)w1f + ((size_t)ks*64 + l)*8);
            acc = __builtin_amdgcn_mfma_f32_16x16x32_bf16(af, bf, acc, 0, 0, 0);
        }
        #pragma unroll
        for (int r = 0; r < 4; ++r)
            Cp[(w*16 + q*4 + r)*17 + r16] = acc[r];
    }
    __syncthreads();
    // ---- MLP + pos ----
    {
        int kp = t >> 4, o = t & 15;
        float sum = Cp[(0*16 + kp)*17 + o] + Cp[(1*16 + kp)*17 + o]
                  + Cp[(2*16 + kp)*17 + o] + Cp[(3*16 + kp)*17 + o];
        hLr[kp*17 + o] = fmaxf(sum + b1[o], 0.f);
        __syncthreads();
        float acc2 = b2[o];
        #pragma unroll
        for (int oo = 0; oo < 16; ++oo)
            acc2 += hLr[kp*17 + oo] * W2s[o][oo];
        acc2 = fminf(fmaxf(acc2, -MAXOFF), MAXOFF);
        int d = o >> 3, p = o & 7;
        int gk = kp0 + kp;
        out_off[((size_t)gk*NP + p)*2 + d] = acc2;
        posL[kp][p][d] = (d ? kwy[kp] : kwx[kp]) + acc2;
    }
    __syncthreads();   // Cp/hL dead; smem becomes featL

    // ---- Phase B: bilinear gather -> featL (LDS) ----
    __hip_bfloat16* featL = (__hip_bfloat16*)smem;
    {
        int half = t >> 5, lane32 = t & 31;
        int c0 = lane32 * 4;
        #pragma unroll 4
        for (int s = 0; s < 16; ++s) {
            int pr = s*8 + half;
            int kp = pr >> 3, p = pr & 7;
            float px = posL[kp][p][0], py = posL[kp][p][1];
            float x0f = floorf(px), y0f = floorf(py);
            int x0 = (int)x0f, y0 = (int)y0f;
            float wx1 = px - x0f, wy1 = py - y0f;
            float wx0 = 1.f - wx1, wy0 = 1.f - wy1;
            float a0 = 0.f, a1 = 0.f, a2 = 0.f, a3 = 0.f;
            #pragma unroll
            for (int tap = 0; tap < 4; ++tap) {
                int xi = x0 + (tap & 1);
                int yi = y0 + (tap >> 1);
                float wgt = ((tap & 1) ? wx1 : wx0) * ((tap >> 1) ? wy1 : wy0);
                bool valid = (xi >= 0) & (xi < W_) & (yi >= 0) & (yi < H_);
                int xc = min(max(xi, 0), W_-1);
                int yc = min(max(yi, 0), H_-1);
                float wv = valid ? wgt : 0.f;
                const __hip_bfloat16* src = xtb + ((size_t)(i*H_ + yc)*W_ + xc)*C_ + c0;
                s16x4 v = *(const s16x4*)src;
                a0 += wv * bf2f(v[0]);
                a1 += wv * bf2f(v[1]);
                a2 += wv * bf2f(v[2]);
                a3 += wv * bf2f(v[3]);
            }
            s16x4 ov;
            ov[0] = f2bf_s(a0); ov[1] = f2bf_s(a1);
            ov[2] = f2bf_s(a2); ov[3] = f2bf_s(a3);
            *(s16x4*)(featL + kp*FSTR + p*C_ + c0) = ov;
        }
    }
    __syncthreads();

    // ---- Phase C: preload ALL A-frags, then featL region is reused ----
    s16x8 af[2][4];
    #pragma unroll
    for (int pi = 0; pi < 2; ++pi) {
        int p = w*2 + pi;
        #pragma unroll
        for (int ks = 0; ks < 4; ++ks)
            af[pi][ks] = *(const s16x8*)(featL + r16*FSTR + p*C_ + ks*32 + q*8);
    }
    __syncthreads();   // all featL reads done; smem becomes Hl (per-wave) / red

    __hip_bfloat16* Hl = (__hip_bfloat16*)(smem + (size_t)w*8448);  // [16][HSTR]
    f32x4 dacc[8];
    #pragma unroll
    for (int jd = 0; jd < 8; ++jd) dacc[jd] = (f32x4){0.f,0.f,0.f,0.f};
    #pragma unroll
    for (int pi = 0; pi < 2; ++pi) {
        int p = w*2 + pi;
        #pragma unroll
        for (int j = 0; j < 8; ++j) {
            f32x4 acc = (f32x4){0.f,0.f,0.f,0.f};
            const short* sb = (const short*)sfb + ((j*4)*64 + l)*8;
            #pragma unroll
            for (int ks = 0; ks < 4; ++ks)
                acc = __builtin_amdgcn_mfma_f32_16x16x32_bf16(af[pi][ks], *(const s16x8*)(sb + ks*512), acc, 0, 0, 0);
            #pragma unroll
            for (int r = 0; r < 4; ++r) {
                float v = acc[r];
                v = v > 0.f ? SELU_SC*v : SELU_SC*SELU_AL*expm1f(v);
                Hl[(q*4 + r)*HSTR + j*16 + r16] = __float2bfloat16(v);
            }
        }
        s16x8 ah[4];
        #pragma unroll
        for (int ks = 0; ks < 4; ++ks)
            ah[ks] = *(const s16x8*)(Hl + r16*HSTR + ks*32 + q*8);
        #pragma unroll
        for (int jd = 0; jd < 8; ++jd) {
            const short* ab = (const short*)aggb + (((jd*8 + p)*4)*64 + l)*8;
            #pragma unroll
            for (int ks = 0; ks < 4; ++ks)
                dacc[jd] = __builtin_amdgcn_mfma_f32_16x16x32_bf16(ah[ks], *(const s16x8*)(ab + ks*512), dacc[jd], 0, 0, 0);
        }
    }
    __syncthreads();   // all Hl reads done; smem becomes red [4][16][RSTR]

    float* red = (float*)smem;
    #pragma unroll
    for (int jd = 0; jd < 8; ++jd)
        #pragma unroll
        for (int r = 0; r < 4; ++r)
            red[((size_t)w*16 + q*4 + r)*RSTR + jd*16 + r16] = dacc[jd][r];
    __syncthreads();

    // ---- fused L2-normalize + store ----
    {
        int row = t >> 4, c0 = t & 15;
        float v[8];
        float ss = 0.f;
        #pragma unroll
        for (int k = 0; k < 8; ++k) {
            int col = c0 + 16*k;
            float s = red[(0*16 + row)*RSTR + col] + red[(1*16 + row)*RSTR + col]
                    + red[(2*16 + row)*RSTR + col] + red[(3*16 + row)*RSTR + col];
            v[k] = s; ss += s*s;
        }
        ss += __shfl_xor(ss, 1);
        ss += __shfl_xor(ss, 2);
        ss += __shfl_xor(ss, 4);
        ss += __shfl_xor(ss, 8);
        float sc = fmaxf(sqrtf(ss), 1e-12f);
        #pragma unroll
        for (int k = 0; k < 8; ++k)
            descs[(size_t)(kp0 + row)*C_ + c0 + 16*k] = v[k] / sc;
    }
}

// ---------------- fallback path (no workspace): fp32 direct -----------------
__global__ __launch_bounds__(64) void k_offsets_f32(const float* __restrict__ xin,
        const float* __restrict__ kpts, const float* __restrict__ W1,
        const float* __restrict__ b1, const float* __restrict__ W2,
        const float* __restrict__ b2, float* __restrict__ out_off,
        float* __restrict__ pos) {
    __shared__ float pL[1152];
    __shared__ float hL2[16];
    __shared__ float oL[16];
    int bid = blockIdx.x;
    int i = bid >> 11;
    int t = threadIdx.x;
    float kx = kpts[(size_t)bid*2 + 0];
    float ky = kpts[(size_t)bid*2 + 1];
    float kwhx = (kx*0.5f + 0.5f) * (float)(W_-1);
    float kwhy = (ky*0.5f + 0.5f) * (float)(H_-1);
    int cx = (int)kwhx - 1; cx = cx < 0 ? 0 : (cx > 252 ? 252 : cx);
    int cy = (int)kwhy - 1; cy = cy < 0 ? 0 : (cy > 252 ? 252 : cy);
    for (int e = t; e < 1152; e += 64) {
        int a = e/384; int r = e - a*384; int b = r >> 7; int c = r & 127;
        pL[e] = xin[(((size_t)(i*C_ + c))*H_ + cy + a)*W_ + cx + b];
    }
    __syncthreads();
    int o = t & 15;
    int chunk = t >> 4;
    float partial = 0.f;
    const float* w1r = W1 + o*1152;
    for (int c = chunk*32; c < chunk*32 + 32; ++c) {
        #pragma unroll
        for (int ab = 0; ab < 9; ++ab) {
            const int a = ab/3, b = ab - (ab/3)*3;
            partial += w1r[c*9 + ab] * pL[a*384 + b*128 + c];
        }
    }
    partial += __shfl_xor(partial, 16);
    partial += __shfl_xor(partial, 32);
    float h1 = fmaxf(partial + b1[o], 0.f);
    if (t < 16) hL2[t] = h1;
    __syncthreads();
    if (t < 16) {
        float acc = b2[t];
        const float* w2r = W2 + t*16;
        #pragma unroll
        for (int oo = 0; oo < 16; ++oo) acc += w2r[oo]*hL2[oo];
        acc = fminf(fmaxf(acc, -MAXOFF), MAXOFF);
        oL[t] = acc;
    }
    __syncthreads();
    if (t < 8) {
        float ox = oL[t], oy = oL[8 + t];
        size_t base = ((size_t)bid*NP + t)*2;
        out_off[base]   = ox;
        out_off[base+1] = oy;
        pos[base]   = kwhx + ox;
        pos[base+1] = kwhy + oy;
    }
}

__global__ __launch_bounds__(128) void k_sample_f32(const float* __restrict__ xin,
        const float* __restrict__ pos, const float* __restrict__ sf_w,
        const float* __restrict__ agg_w, float* __restrict__ dst) {
    __shared__ __align__(16) float featL[NP*C_];
    __shared__ float pp[16];
    int bid = blockIdx.x;
    int i = bid >> 11;
    int c = threadIdx.x;
    if (c < 16) pp[c] = pos[(size_t)bid*16 + c];
    __syncthreads();
    #pragma unroll
    for (int p = 0; p < NP; ++p) {
        float px = pp[p*2], py = pp[p*2+1];
        float x0f = floorf(px), y0f = floorf(py);
        int x0 = (int)x0f, y0 = (int)y0f;
        float wx1 = px - x0f, wy1 = py - y0f;
        float wx0 = 1.f - wx1, wy0 = 1.f - wy1;
        float acc = 0.f;
        #pragma unroll
        for (int tap = 0; tap < 4; ++tap) {
            int xi = x0 + (tap & 1);
            int yi = y0 + (tap >> 1);
            float w = ((tap & 1) ? wx1 : wx0) * ((tap >> 1) ? wy1 : wy0);
            bool valid = (xi >= 0) & (xi < W_) & (yi >= 0) & (yi < H_);
            int xc = min(max(xi, 0), W_-1);
            int yc = min(max(yi, 0), H_-1);
            acc += (valid ? w : 0.f) * xin[(((size_t)(i*C_ + c))*H_ + yc)*W_ + xc];
        }
        featL[p*C_ + c] = acc;
    }
    __syncthreads();
    float acc[NP];
    #pragma unroll
    for (int p = 0; p < NP; ++p) acc[p] = 0.f;
    const float4* sfr = (const float4*)(sf_w + (size_t)c*C_);
    const float4* fL4 = (const float4*)featL;
    for (int c4 = 0; c4 < C_/4; ++c4) {
        float4 wv = sfr[c4];
        #pragma unroll
        for (int p = 0; p < NP; ++p) {
            float4 f = fL4[p*(C_/4) + c4];
            acc[p] += wv.x*f.x + wv.y*f.y + wv.z*f.z + wv.w*f.w;
        }
    }
    #pragma unroll
    for (int p = 0; p < NP; ++p) {
        float v = acc[p];
        acc[p] = v > 0.f ? SELU_SC*v : SELU_SC*SELU_AL*expm1f(v);
    }
    __shared__ __align__(16) float gL[NP*C_];
    #pragma unroll
    for (int p = 0; p < NP; ++p) gL[p*C_ + c] = acc[p];
    __syncthreads();
    float d_acc = 0.f;
    for (int pc = 0; pc < NP*C_; ++pc)
        d_acc += gL[pc] * agg_w[(size_t)pc*C_ + c];
    dst[(size_t)bid*C_ + c] = d_acc;
}

__global__ __launch_bounds__(64) void k_norm(float* __restrict__ out) {
    int row = blockIdx.x;
    int l = threadIdx.x;
    float* r = out + (size_t)row*C_;
    float a = r[l], b = r[l+64];
    float ss = a*a + b*b;
    #pragma unroll
    for (int m = 1; m < 64; m <<= 1) ss += __shfl_xor(ss, m);
    float s = fmaxf(sqrtf(ss), 1e-12f);
    r[l] = a/s; r[l+64] = b/s;
}

extern "C" void kernel_launch(void* const* d_in, const int* in_sizes, int n_in,
                              void* d_out, int out_size, void* d_ws, size_t ws_size,
                              hipStream_t stream) {
    const float* x    = (const float*)d_in[0];
    const float* kpts = (const float*)d_in[1];
    const float* W1   = (const float*)d_in[2];
    const float* b1   = (const float*)d_in[3];
    const float* W2   = (const float*)d_in[4];
    const float* b2   = (const float*)d_in[5];
    const float* sfw  = (const float*)d_in[6];
    const float* aggw = (const float*)d_in[7];
    float* out_desc = (float*)d_out;
    float* out_off  = out_desc + (size_t)B_*NK*C_;

    char* ws = (char*)d_ws;
    float* pos = (float*)ws;                                  // fallback only
    const size_t W1F_OFF = (size_t)1 << 20;
    const size_t SFB_OFF = (size_t)2 << 20;
    const size_t AGG_OFF = (size_t)3 << 20;
    const size_t XT_OFF  = (size_t)1 << 26;                   // 64 MB
    const size_t XT_BYTES = (size_t)B_*H_*W_*C_*2;            // 64 MB
    bool useXT = ws_size >= XT_OFF + XT_BYTES;
    __hip_bfloat16* xtb  = (__hip_bfloat16*)(ws + XT_OFF);
    __hip_bfloat16* w1f  = (__hip_bfloat16*)(ws + W1F_OFF);
    __hip_bfloat16* sfb  = (__hip_bfloat16*)(ws + SFB_OFF);
    __hip_bfloat16* aggb = (__hip_bfloat16*)(ws + AGG_OFF);

    if (useXT) {
        k_transpose_prep<<<NT_BLK + NP_BLK, 256, 0, stream>>>(x, xtb, W1, sfw, aggw,
                                                              w1f, sfb, aggb);
        k_fused<<<NROWS/16, 256, 0, stream>>>(xtb, kpts, w1f, b1, W2, b2, sfb, aggb,
                                              out_off, out_desc);
    } else {
        k_offsets_f32<<<NROWS, 64, 0, stream>>>(x, kpts, W1, b1, W2, b2, out_off, pos);
        k_sample_f32<<<NROWS, 128, 0, stream>>>(x, pos, sfw, aggw, out_desc);
        k_norm<<<NROWS, 64, 0, stream>>>(out_desc);
    }
}